// Round 9
// baseline (349.081 us; speedup 1.0000x reference)
//
#include <hip/hip_runtime.h>
#include <hip/hip_bf16.h>

#define BN_EPS 1e-5f
constexpr int C = 256;

typedef __attribute__((ext_vector_type(8))) short bf16x8;
typedef __attribute__((ext_vector_type(4))) float f32x4;

static __device__ __forceinline__ unsigned short f2bf(float f) {
    __hip_bfloat16 h = __float2bfloat16(f);
    return *reinterpret_cast<unsigned short*>(&h);
}
static __device__ __forceinline__ float bf2f(unsigned short u) {
    unsigned int v = ((unsigned int)u) << 16;
    return __uint_as_float(v);
}

// Fold BN scale into weights, transpose [N][C][9] f32 -> [9][N][C] bf16.
__global__ __launch_bounds__(256) void wprep(
    const float* __restrict__ w, const float* __restrict__ gamma,
    const float* __restrict__ var, unsigned short* __restrict__ wt)
{
    const int n = blockIdx.x, c = threadIdx.x;
    const float scale = gamma[n] * rsqrtf(var[n] + BN_EPS);
    const float* wp = w + ((size_t)n * C + c) * 9;
#pragma unroll
    for (int k = 0; k < 9; ++k)
        wt[((size_t)k * C + n) * C + c] = f2bf(wp[k] * scale);
}

// fp32 NCHW [g][C][961] -> bf16 CHUNK-MAJOR [g][8][961][32]
// (per-chunk pixel window = 64 B/pixel -> 21.8 KB per 341-pix window: L1-fits)
__global__ __launch_bounds__(256) void nchw_to_cpc(
    const float* __restrict__ in, unsigned short* __restrict__ out)
{
    const int b = blockIdx.z, chk = blockIdx.y, px0 = blockIdx.x * 64;
    const int t = threadIdx.x;
    const int px = px0 + (t >> 2), sl = t & 3;
    if (px >= 961) return;
    const float* ip = in + ((size_t)b * 256 + chk * 32 + sl * 8) * 961 + px;
    bf16x8 pk;
#pragma unroll
    for (int u = 0; u < 8; ++u)
        pk[u] = (short)f2bf(ip[(size_t)u * 961]);
    *(bf16x8*)&out[(((size_t)b * 8 + chk) * 961 + px) * 32 + sl * 8] = pk;
}

// fp32 NCHW [g][C][HW] -> bf16 [g][HW][C] (pixel-major; used for kconv input).
template<int HW>
__global__ __launch_bounds__(256) void nchw_to_pc(
    const float* __restrict__ in, unsigned short* __restrict__ out)
{
    __shared__ float s_t[64][65];
    const int b = blockIdx.z, c0 = blockIdx.y * 64, px0 = blockIdx.x * 64;
    const int t = threadIdx.x;
    const float* ip = in + ((size_t)b * C + c0) * HW;

#pragma unroll
    for (int it = 0; it < 4; ++it) {
        int i = t + it * 256;
        int cl = i >> 4, q = i & 15;
#pragma unroll
        for (int j = 0; j < 4; ++j) {
            int p = px0 + q * 4 + j;
            s_t[cl][q * 4 + j] = (p < HW) ? ip[(size_t)cl * HW + p] : 0.f;
        }
    }
    __syncthreads();

    unsigned short* op = out + (size_t)b * HW * C + (size_t)px0 * C + c0;
#pragma unroll
    for (int it = 0; it < 2; ++it) {
        int i = t + it * 256;
        int pl = i >> 3, gq = i & 7;
        if (px0 + pl < HW) {
            bf16x8 pk;
#pragma unroll
            for (int u = 0; u < 8; ++u)
                pk[u] = (short)f2bf(s_t[gq * 8 + u][pl]);
            *(bf16x8*)&op[(size_t)pl * C + gq * 8] = pk;
        }
    }
}

// ---------------------------------------------------------------------------
// SEARCH CONV v5: A direct-from-global (chunk-major layout, L1-resident
// 21.8 KB window per chunk), B in LDS with paired-step barriers + 4 buffers.
// Block: 512 thr = 8 waves (2 wm x 4 wn). BM=224, BN=256, wave tile 112x64.
// K-steps s = 0..71 (chunk = s/9, tap = s%9); barrier every two steps.
// ---------------------------------------------------------------------------
__global__ __launch_bounds__(512, 2) void sconv_mfma(
    const unsigned short* __restrict__ in,   // [g][8][961][32] bf16
    const unsigned short* __restrict__ wt,   // [9][256][256] bf16
    const float* __restrict__ gamma, const float* __restrict__ beta,
    const float* __restrict__ mean, const float* __restrict__ var,
    unsigned short* __restrict__ outp)       // [g][256][844] bf16
{
    constexpr int WOUT = 29, NPOS = 841;
    constexpr int BM = 224, MF = 7, NF = 4;
    constexpr int LDK = 40;                  // B rows: 32 ch + 8 pad (80B)
    constexpr int BBUF = 256 * LDK;          // 10240 shorts per B buffer
    constexpr int BIT = 2;                   // 256*4 / 512

    __shared__ __align__(16) short s_b[4 * BBUF];   // 81,920 B

    const int t = threadIdx.x;
    const int lane = t & 63, wave = t >> 6;
    const int wm = wave >> 2, wn = wave & 3;
    const int lr = lane >> 4, lc = lane & 15;

    const int p0 = blockIdx.x * BM;          // 0,224,448,672
    const int b  = blockIdx.y;

    const unsigned short* in_cb = in + (size_t)b * (8 * 961 * 32);

    // A fragment pixel indices (clamped); addr = chunk*961*32 + (pix+dt)*32 + lr*8
    int apix[MF];
#pragma unroll
    for (int m = 0; m < MF; ++m) {
        int pm = wm * 112 + m * 16 + lc;
        int p = p0 + pm; p = p < NPOS ? p : NPOS - 1;
        int y = p / WOUT, x = p - y * WOUT;
        apix[m] = y * 31 + x;
    }

    // B staging decomposition
    const unsigned short* bptr[BIT]; int boff[BIT];
#pragma unroll
    for (int it = 0; it < BIT; ++it) {
        int i = t + it * 512;
        int n = i >> 2, sl = i & 3;
        bptr[it] = wt + (size_t)n * 256 + sl * 8;
        boff[it] = n * LDK + sl * 8;
    }

    f32x4 acc[MF][NF];
#pragma unroll
    for (int m = 0; m < MF; ++m)
#pragma unroll
        for (int n = 0; n < NF; ++n) acc[m][n] = f32x4{0.f, 0.f, 0.f, 0.f};

#define LOAD_AF(dst, S)                                                        \
    {                                                                          \
        const int ch_ = (S) / 9, tap_ = (S) % 9;                               \
        const int dt_ = (tap_ / 3) * 31 + (tap_ % 3);                          \
        const size_t cb_ = (size_t)ch_ * (961 * 32);                           \
        _Pragma("unroll")                                                      \
        for (int m = 0; m < MF; ++m)                                           \
            dst[m] = *(const bf16x8*)(in_cb + cb_ + (size_t)(apix[m] + dt_) * 32 + lr * 8); \
    }

#define DO_STEP(S, AF)                                                         \
    {                                                                          \
        const int bb_ = ((S) & 3) * BBUF;                                      \
        bf16x8 bfr[NF];                                                        \
        _Pragma("unroll")                                                      \
        for (int n = 0; n < NF; ++n)                                           \
            bfr[n] = *(const bf16x8*)&s_b[bb_ + (wn * 64 + n * 16 + lc) * LDK + lr * 8]; \
        _Pragma("unroll")                                                      \
        for (int m = 0; m < MF; ++m)                                           \
            _Pragma("unroll")                                                  \
            for (int n = 0; n < NF; ++n)                                       \
                acc[m][n] = __builtin_amdgcn_mfma_f32_16x16x32_bf16(           \
                    AF[m], bfr[n], acc[m][n], 0, 0, 0);                        \
    }

    bf16x8 bstg0[BIT], bstg1[BIT];
    bf16x8 af0[MF], af1[MF];

    // ---- prologue: B steps 0,1 -> buffers 0,1; A frags for steps 0,1 ----
#pragma unroll
    for (int it = 0; it < BIT; ++it)
        bstg0[it] = __builtin_nontemporal_load((const bf16x8*)bptr[it]);
#pragma unroll
    for (int it = 0; it < BIT; ++it)
        bstg1[it] = __builtin_nontemporal_load((const bf16x8*)(bptr[it] + 65536));
    LOAD_AF(af0, 0)
    LOAD_AF(af1, 1)
#pragma unroll
    for (int it = 0; it < BIT; ++it) *(bf16x8*)&s_b[boff[it]] = bstg0[it];
#pragma unroll
    for (int it = 0; it < BIT; ++it) *(bf16x8*)&s_b[BBUF + boff[it]] = bstg1[it];
    __syncthreads();

#pragma unroll 1
    for (int pr = 0; pr < 36; ++pr) {
        const int s0 = 2 * pr, s1 = s0 + 1;

        // pair-top: issue B loads for steps s0+2, s1+2 (nontemporal — keep L1 for A)
        if (pr < 35) {
            const int u0 = s0 + 2, u1 = s1 + 2;
            const int t0 = u0 % 9, c0_ = (u0 / 9) * 32;
            const int t1 = u1 % 9, c1_ = (u1 / 9) * 32;
#pragma unroll
            for (int it = 0; it < BIT; ++it)
                bstg0[it] = __builtin_nontemporal_load(
                    (const bf16x8*)(bptr[it] + (size_t)t0 * 65536 + c0_));
#pragma unroll
            for (int it = 0; it < BIT; ++it)
                bstg1[it] = __builtin_nontemporal_load(
                    (const bf16x8*)(bptr[it] + (size_t)t1 * 65536 + c1_));
        }

        DO_STEP(s0, af0)
        if (pr < 35) { LOAD_AF(af0, s0 + 2) }    // L1-hit, lands before next pair

        DO_STEP(s1, af1)
        if (pr < 35) {
            LOAD_AF(af1, s1 + 2)
            const int w0 = ((s0 + 2) & 3) * BBUF, w1 = ((s1 + 2) & 3) * BBUF;
#pragma unroll
            for (int it = 0; it < BIT; ++it)
                *(bf16x8*)&s_b[w0 + boff[it]] = bstg0[it];
#pragma unroll
            for (int it = 0; it < BIT; ++it)
                *(bf16x8*)&s_b[w1 + boff[it]] = bstg1[it];
        }
        __syncthreads();
    }
#undef DO_STEP
#undef LOAD_AF

    // ---- epilogue: bias + relu -> bf16 planes (padded stride 844) ----
#pragma unroll
    for (int n = 0; n < NF; ++n) {
        const int co = wn * 64 + n * 16 + lc;
        const float sc = gamma[co] * rsqrtf(var[co] + BN_EPS);
        const float bias = beta[co] - mean[co] * sc;
#pragma unroll
        for (int m = 0; m < MF; ++m) {
            int pm = wm * 112 + m * 16 + lr * 4;
            int p = p0 + pm;
            f32x4 v = acc[m][n];
            float r0 = fmaxf(v.x + bias, 0.f);
            float r1 = fmaxf(v.y + bias, 0.f);
            float r2 = fmaxf(v.z + bias, 0.f);
            float r3 = fmaxf(v.w + bias, 0.f);
            unsigned short* op = outp + ((size_t)b * C + co) * 844 + p;
            if (p + 4 <= NPOS) {
                ushort4 pk;
                pk.x = f2bf(r0); pk.y = f2bf(r1); pk.z = f2bf(r2); pk.w = f2bf(r3);
                *(ushort4*)op = pk;
            } else {
                float rr[4] = {r0, r1, r2, r3};
#pragma unroll
                for (int i = 0; i < 4; ++i)
                    if (p + i < NPOS) op[i] = f2bf(rr[i]);
            }
        }
    }
}

// ---------------------------------------------------------------------------
// KERNEL CONV (small, 7x7 -> 5x5): B from global, A async-staged in LDS.
// Input ipk stays pixel-major [g][49][256].
// ---------------------------------------------------------------------------
template<int HIN, int WOUT, int BPB, int BM, int BN_, int MF, int NF, bool OUT_BF16, int OSTRIDE>
__global__ __launch_bounds__(256, 3) void conv3_mfma(
    const unsigned short* __restrict__ in,
    const unsigned short* __restrict__ wt,
    const float* __restrict__ gamma, const float* __restrict__ beta,
    const float* __restrict__ mean, const float* __restrict__ var,
    void* __restrict__ outv)
{
    constexpr int WIN = HIN, HW = HIN * WIN;
    constexpr int NPOS = WOUT * WOUT;
    constexpr int PPB = BM / BPB;
    constexpr int NMT = (NPOS + PPB - 1) / PPB;
    constexpr int NR0 = (PPB - 1) / WOUT + 4;
    constexpr int NROWS = NR0 < HIN ? NR0 : HIN;
    constexpr int APIX = NROWS * WIN;
    constexpr int LDK = 40;
    constexpr int SLOTS_B = APIX * 4;
    constexpr int SLOTS = BPB * SLOTS_B;
    constexpr int ITERS = (SLOTS + 255) / 256;

    __shared__ __align__(16) short s_a[BPB * APIX * LDK];

    const int t = threadIdx.x;
    const int lane = t & 63, wave = t >> 6;
    const int wm = wave >> 1, wn = wave & 1;
    const int lr = lane >> 4, lc = lane & 15;

    const int mt = blockIdx.x % NMT, nt = blockIdx.x / NMT;
    const int p0 = mt * PPB, n0 = nt * BN_;
    const int b0 = blockIdx.y * BPB;
    const int y0 = p0 / WOUT;
    const int R = (HIN - y0) < NROWS ? (HIN - y0) : NROWS;
    const int npix = R * WIN;

    int arow[MF];
#pragma unroll
    for (int m = 0; m < MF; ++m) {
        int pm = wm * MF * 16 + m * 16 + lc;
        int bb = pm / PPB;
        int p = p0 + (pm % PPB);
        p = p < NPOS ? p : NPOS - 1;
        int y = p / WOUT, x = p % WOUT;
        arow[m] = (bb * APIX + (y - y0) * WIN + x) * LDK;
    }

    f32x4 acc[MF][NF];
#pragma unroll
    for (int m = 0; m < MF; ++m)
#pragma unroll
        for (int n = 0; n < NF; ++n) acc[m][n] = f32x4{0.f, 0.f, 0.f, 0.f};

    int sbb[ITERS], spx[ITERS], ssl[ITERS];
#pragma unroll
    for (int it = 0; it < ITERS; ++it) {
        int i = t + it * 256;
        int ii = i < SLOTS ? i : 0;
        int bb = (BPB == 1) ? 0 : (ii / SLOTS_B);
        int r = ii - bb * SLOTS_B;
        int px = r >> 2;
        sbb[it] = bb; spx[it] = px < npix ? px : 0; ssl[it] = r & 3;
    }

    const unsigned short* wb = wt + (size_t)(n0 + wn * (NF * 16) + lc) * C + lr * 8;

#define LOAD_STG(c0_)                                                          \
    _Pragma("unroll")                                                          \
    for (int it = 0; it < ITERS; ++it) {                                       \
        const unsigned short* sp =                                             \
            in + ((size_t)(b0 + sbb[it]) * HW + (size_t)(y0 * WIN + spx[it])) * C \
               + (c0_) + ssl[it] * 8;                                          \
        stg[it] = *(const bf16x8*)sp;                                          \
    }

#define WRITE_STG()                                                            \
    _Pragma("unroll")                                                          \
    for (int it = 0; it < ITERS; ++it)                                         \
        *(bf16x8*)&s_a[(sbb[it] * APIX + spx[it]) * LDK + ssl[it] * 8] = stg[it];

    {
        bf16x8 stg[ITERS];
        LOAD_STG(0)
        WRITE_STG()
    }

#pragma unroll 1
    for (int ch = 0; ch < 8; ++ch) {
        const int c0 = ch * 32;
        __syncthreads();

        bf16x8 stg[ITERS];
        if (ch < 7) { LOAD_STG(c0 + 32) }

        bf16x8 bcur[NF], bnxt[NF];
#pragma unroll
        for (int n = 0; n < NF; ++n)
            bnxt[n] = *(const bf16x8*)&wb[0 * (size_t)(C * C) + n * (16 * C) + c0];

#pragma unroll
        for (int tap = 0; tap < 9; ++tap) {
            const int dy = tap / 3, dx = tap % 3;
#pragma unroll
            for (int n = 0; n < NF; ++n) bcur[n] = bnxt[n];
            if (tap < 8) {
#pragma unroll
                for (int n = 0; n < NF; ++n)
                    bnxt[n] = *(const bf16x8*)&wb[(size_t)(tap + 1) * (C * C) + n * (16 * C) + c0];
            }
            bf16x8 af[MF];
#pragma unroll
            for (int m = 0; m < MF; ++m)
                af[m] = *(const bf16x8*)&s_a[arow[m] + (dy * WIN + dx) * LDK + lr * 8];
#pragma unroll
            for (int m = 0; m < MF; ++m)
#pragma unroll
                for (int n = 0; n < NF; ++n)
                    acc[m][n] = __builtin_amdgcn_mfma_f32_16x16x32_bf16(
                        af[m], bcur[n], acc[m][n], 0, 0, 0);
        }

        __syncthreads();
        if (ch < 7) { WRITE_STG() }
    }
#undef LOAD_STG
#undef WRITE_STG

#pragma unroll
    for (int n = 0; n < NF; ++n) {
        const int co = n0 + wn * NF * 16 + n * 16 + lc;
        const float sc = gamma[co] * rsqrtf(var[co] + BN_EPS);
        const float bias = beta[co] - mean[co] * sc;
#pragma unroll
        for (int m = 0; m < MF; ++m) {
            int pm = wm * MF * 16 + m * 16 + lr * 4;
            int bb = pm / PPB;
            int p = p0 + (pm % PPB);
            int b = b0 + bb;
            f32x4 v = acc[m][n];
            float r0 = fmaxf(v.x + bias, 0.f);
            float r1 = fmaxf(v.y + bias, 0.f);
            float r2 = fmaxf(v.z + bias, 0.f);
            float r3 = fmaxf(v.w + bias, 0.f);
            if (OUT_BF16) {
                unsigned short* op = (unsigned short*)outv + ((size_t)b * C + co) * OSTRIDE + p;
                if (p + 4 <= NPOS) {
                    ushort4 pk;
                    pk.x = f2bf(r0); pk.y = f2bf(r1); pk.z = f2bf(r2); pk.w = f2bf(r3);
                    *(ushort4*)op = pk;
                } else {
                    float rr[4] = {r0, r1, r2, r3};
#pragma unroll
                    for (int i = 0; i < 4; ++i)
                        if (p + i < NPOS) op[i] = f2bf(rr[i]);
                }
            } else {
                float* op = (float*)outv + ((size_t)b * C + co) * OSTRIDE + p;
                float rr[4] = {r0, r1, r2, r3};
#pragma unroll
                for (int i = 0; i < 4; ++i)
                    if (p + i < NPOS) op[i] = rr[i];
            }
        }
    }
}

// Depthwise 5x5 valid xcorr: s bf16 [g,C,844], k f32 [g,C,28] -> out f32 [g,C,625].
__global__ __launch_bounds__(256) void xcorr_dw(
    const unsigned short* __restrict__ s, const float* __restrict__ k,
    float* __restrict__ out)
{
    const int bc = blockIdx.x;
    const unsigned short* sp = s + (size_t)bc * 844;
    const float* kp = k + (size_t)bc * 28;
    float* op = out + (size_t)bc * 625;

    __shared__ float s_s[844];
    __shared__ float s_k[25];
    const int t = threadIdx.x;
    if (t < 211) {
        ushort4 v = *(const ushort4*)(sp + 4 * t);
        s_s[4 * t + 0] = bf2f(v.x);
        s_s[4 * t + 1] = bf2f(v.y);
        s_s[4 * t + 2] = bf2f(v.z);
        s_s[4 * t + 3] = bf2f(v.w);
    }
    if (t < 25) s_k[t] = kp[t];
    __syncthreads();

    float kk[25];
#pragma unroll
    for (int i = 0; i < 25; ++i) kk[i] = s_k[i];

#pragma unroll
    for (int j = 0; j < 3; ++j) {
        int pos = t + j * 256;
        if (pos < 625) {
            int y = pos / 25, x = pos - y * 25;
            float a = 0.f;
#pragma unroll
            for (int dy = 0; dy < 5; ++dy)
#pragma unroll
                for (int dx = 0; dx < 5; ++dx)
                    a += s_s[(y + dy) * 29 + x + dx] * kk[dy * 5 + dx];
            op[pos] = a;
        }
    }
}

extern "C" void kernel_launch(void* const* d_in, const int* in_sizes, int n_in,
                              void* d_out, int out_size, void* d_ws, size_t ws_size,
                              hipStream_t stream) {
    const float* kin = (const float*)d_in[0];   // [128,256,7,7]
    const float* sin_ = (const float*)d_in[1];  // [128,256,31,31]
    const float* wk = (const float*)d_in[2];
    const float* bkg = (const float*)d_in[3];
    const float* bkb = (const float*)d_in[4];
    const float* bkm = (const float*)d_in[5];
    const float* bkv = (const float*)d_in[6];
    const float* ws_ = (const float*)d_in[7];
    const float* bsg = (const float*)d_in[8];
    const float* bsb = (const float*)d_in[9];
    const float* bsm = (const float*)d_in[10];
    const float* bsv = (const float*)d_in[11];
    float* out = (float*)d_out;

    char* base = (char*)d_ws;
    unsigned short* wkt = (unsigned short*)base;               // 1,179,648 B
    unsigned short* wst = wkt + (size_t)9 * C * C;
    char* gbase = base + 2359296;

    const size_t perb_is = (size_t)961 * C * 2;  // 492032 (chunk-major, same bytes)
    const size_t perb_ik = (size_t)49 * C * 2;   // 25088
    const size_t perb_sb = (size_t)844 * C * 2;  // 432128
    const size_t perb_kb = (size_t)28 * C * 4;   // 28672
    const size_t perb = perb_is + perb_ik + perb_sb + perb_kb; // 977920

    int G = (int)((ws_size - 2359296) / perb);
    if (G > 128) G = 128;
    G &= ~1;
    if (G < 2) G = 2;

    unsigned short* ips  = (unsigned short*)gbase;
    unsigned short* ipk  = (unsigned short*)(gbase + (size_t)G * perb_is);
    unsigned short* sbuf = (unsigned short*)(gbase + (size_t)G * (perb_is + perb_ik));
    float*          kbuf = (float*)(gbase + (size_t)G * (perb_is + perb_ik + perb_sb));

    wprep<<<C, 256, 0, stream>>>(wk, bkg, bkv, wkt);
    wprep<<<C, 256, 0, stream>>>(ws_, bsg, bsv, wst);

    for (int g0 = 0; g0 < 128; g0 += G) {
        const int g = (128 - g0) < G ? (128 - g0) : G;

        // search input -> chunk-major [g][8][961][32]
        nchw_to_cpc<<<dim3(16, 8, g), 256, 0, stream>>>(
            sin_ + (size_t)g0 * C * 961, ips);
        // kernel input -> pixel-major [g][49][256]
        nchw_to_pc<49><<<dim3(1, 4, g), 256, 0, stream>>>(
            kin + (size_t)g0 * C * 49, ipk);

        // kernel conv: 7x7 -> 5x5. BPB=2, BM=64, BN=128, MF=2, NF=4, f32 out.
        conv3_mfma<7, 5, 2, 64, 128, 2, 4, false, 28>
            <<<dim3(2, g / 2), 256, 0, stream>>>(ipk, wkt, bkg, bkb, bkm, bkv, kbuf);

        // search conv v5: A-direct (L1-resident chunk window), B in LDS paired.
        sconv_mfma<<<dim3(4, g), 512, 0, stream>>>(
            ips, wst, bsg, bsb, bsm, bsv, sbuf);

        xcorr_dw<<<(unsigned)g * C, 256, 0, stream>>>(sbuf, kbuf, out + (size_t)g0 * C * 625);
    }
}

// Round 10
// 304.118 us; speedup vs baseline: 1.1478x; 1.1478x over previous
//
#include <hip/hip_runtime.h>
#include <hip/hip_bf16.h>

#define BN_EPS 1e-5f
constexpr int C = 256;

typedef __attribute__((ext_vector_type(8))) short bf16x8;
typedef __attribute__((ext_vector_type(4))) float f32x4;

static __device__ __forceinline__ unsigned short f2bf(float f) {
    __hip_bfloat16 h = __float2bfloat16(f);
    return *reinterpret_cast<unsigned short*>(&h);
}
static __device__ __forceinline__ float bf2f(unsigned short u) {
    unsigned int v = ((unsigned int)u) << 16;
    return __uint_as_float(v);
}

// Fold BN scale into weights, transpose [N][C][9] f32 -> [9][N][C] bf16.
__global__ __launch_bounds__(256) void wprep(
    const float* __restrict__ w, const float* __restrict__ gamma,
    const float* __restrict__ var, unsigned short* __restrict__ wt)
{
    const int n = blockIdx.x, c = threadIdx.x;
    const float scale = gamma[n] * rsqrtf(var[n] + BN_EPS);
    const float* wp = w + ((size_t)n * C + c) * 9;
#pragma unroll
    for (int k = 0; k < 9; ++k)
        wt[((size_t)k * C + n) * C + c] = f2bf(wp[k] * scale);
}

// fp32 NCHW [g][C][HW] -> bf16 [g][HW][C] (pixel-major, channel-contiguous).
template<int HW>
__global__ __launch_bounds__(256) void nchw_to_pc(
    const float* __restrict__ in, unsigned short* __restrict__ out)
{
    __shared__ float s_t[64][65];
    const int b = blockIdx.z, c0 = blockIdx.y * 64, px0 = blockIdx.x * 64;
    const int t = threadIdx.x;
    const float* ip = in + ((size_t)b * C + c0) * HW;

#pragma unroll
    for (int it = 0; it < 4; ++it) {
        int i = t + it * 256;
        int cl = i >> 4, q = i & 15;
#pragma unroll
        for (int j = 0; j < 4; ++j) {
            int p = px0 + q * 4 + j;
            s_t[cl][q * 4 + j] = (p < HW) ? ip[(size_t)cl * HW + p] : 0.f;
        }
    }
    __syncthreads();

    unsigned short* op = out + (size_t)b * HW * C + (size_t)px0 * C + c0;
#pragma unroll
    for (int it = 0; it < 2; ++it) {
        int i = t + it * 256;
        int pl = i >> 3, gq = i & 7;
        if (px0 + pl < HW) {
            bf16x8 pk;
#pragma unroll
            for (int u = 0; u < 8; ++u)
                pk[u] = (short)f2bf(s_t[gq * 8 + u][pl]);
            *(bf16x8*)&op[(size_t)pl * C + gq * 8] = pk;
        }
    }
}

// ---------------------------------------------------------------------------
// SEARCH CONV v6 (r8 skeleton, 3-step barrier groups):
// 31x31 -> 29x29 implicit-GEMM bf16 MFMA. A and B both staged in LDS.
// Block: 512 thr = 8 waves (2 wm x 4 wn). BM=224, BN=256, wave tile 112x64.
// K-steps s = 0..71 (chunk = s/9, tap = s%9). B: 6 buffers (LDK=36), barrier
// every THREE steps (read {s..s+2} mod 6, write {s+3..s+5} mod 6 — disjoint).
// B loads for group g+1 issued at top of group g. A: 2 buffers; loads issued
// at group 3c top (chunk c), written at end of group 3c+2.
// ---------------------------------------------------------------------------
__global__ __launch_bounds__(512, 2) void sconv_mfma(
    const unsigned short* __restrict__ in,   // [g][961][256] bf16
    const unsigned short* __restrict__ wt,   // [9][256][256] bf16
    const float* __restrict__ gamma, const float* __restrict__ beta,
    const float* __restrict__ mean, const float* __restrict__ var,
    unsigned short* __restrict__ outp)       // [g][256][844] bf16
{
    constexpr int WOUT = 29, NPOS = 841;
    constexpr int BM = 224, MF = 7, NF = 4;
    constexpr int LDK = 36;                  // 32 ch + 4 pad (72B rows)
    constexpr int ROWS = 11;
    constexpr int APIX = ROWS * 31;          // 341
    constexpr int ABUF = APIX * LDK;         // 12276 shorts
    constexpr int BBUF = 256 * LDK;          // 9216 shorts
    constexpr int AIT = 3;                   // ceil(341*4 / 512)
    constexpr int BIT = 2;                   // 256*4 / 512

    __shared__ __align__(16) short s_a[2 * ABUF];   //  49,104 B
    __shared__ __align__(16) short s_b[6 * BBUF];   // 110,592 B (total 159,696)

    const int t = threadIdx.x;
    const int lane = t & 63, wave = t >> 6;
    const int wm = wave >> 2, wn = wave & 3;
    const int lr = lane >> 4, lc = lane & 15;

    const int p0 = blockIdx.x * BM;          // 0,224,448,672
    const int b  = blockIdx.y;
    const int y0 = p0 / WOUT;
    const int R  = min(ROWS, 31 - y0);
    const int npix = R * 31;

    const unsigned short* in_b = in + (size_t)b * (961 * 256);

    // A fragment bases (short index within an A buffer, dy=dx=0)
    int arow[MF];
#pragma unroll
    for (int m = 0; m < MF; ++m) {
        int pm = wm * 112 + m * 16 + lc;
        int p = p0 + pm; p = p < NPOS ? p : NPOS - 1;
        int y = p / WOUT, x = p - y * WOUT;
        arow[m] = ((y - y0) * 31 + x) * LDK + lr * 8;
    }

    // staging decomposition
    const unsigned short* aptr[AIT]; int aoff[AIT];
#pragma unroll
    for (int it = 0; it < AIT; ++it) {
        int i = t + it * 512;
        int px = i >> 2, sl = i & 3;
        px = px < npix ? px : 0;             // idempotent dup of slot 0
        aptr[it] = in_b + (size_t)(y0 * 31 + px) * 256 + sl * 8;
        aoff[it] = px * LDK + sl * 8;
    }
    const unsigned short* bptr[BIT]; int boff[BIT];
#pragma unroll
    for (int it = 0; it < BIT; ++it) {
        int i = t + it * 512;
        int n = i >> 2, sl = i & 3;
        bptr[it] = wt + (size_t)n * 256 + sl * 8;
        boff[it] = n * LDK + sl * 8;
    }

    f32x4 acc[MF][NF];
#pragma unroll
    for (int m = 0; m < MF; ++m)
#pragma unroll
        for (int n = 0; n < NF; ++n) acc[m][n] = f32x4{0.f, 0.f, 0.f, 0.f};

    bf16x8 bstg[3][BIT], astg[AIT];

    // ---- prologue: stage B steps 0,1,2 -> buffers 0,1,2; A chunk 0 ----
#pragma unroll
    for (int q = 0; q < 3; ++q)
#pragma unroll
        for (int it = 0; it < BIT; ++it)
            bstg[q][it] = *(const bf16x8*)(bptr[it] + (size_t)q * 65536);
#pragma unroll
    for (int it = 0; it < AIT; ++it) astg[it] = *(const bf16x8*)(aptr[it]);
#pragma unroll
    for (int q = 0; q < 3; ++q)
#pragma unroll
        for (int it = 0; it < BIT; ++it)
            *(bf16x8*)&s_b[q * BBUF + boff[it]] = bstg[q][it];
#pragma unroll
    for (int it = 0; it < AIT; ++it) *(bf16x8*)&s_a[aoff[it]] = astg[it];
    __syncthreads();

#define DO_STEP(S)                                                             \
    {                                                                          \
        const int tap_ = (S) % 9;                                              \
        const int dt_ = (tap_ / 3) * 31 + (tap_ % 3);                          \
        const int ab_ = (((S) / 9) & 1) * ABUF;                                \
        const int bb_ = ((S) % 6) * BBUF;                                      \
        bf16x8 bfr[NF], af[MF];                                                \
        _Pragma("unroll")                                                      \
        for (int n = 0; n < NF; ++n)                                           \
            bfr[n] = *(const bf16x8*)&s_b[bb_ + (wn * 64 + n * 16 + lc) * LDK + lr * 8]; \
        _Pragma("unroll")                                                      \
        for (int m = 0; m < MF; ++m)                                           \
            af[m] = *(const bf16x8*)&s_a[ab_ + arow[m] + dt_ * LDK];           \
        _Pragma("unroll")                                                      \
        for (int m = 0; m < MF; ++m)                                           \
            _Pragma("unroll")                                                  \
            for (int n = 0; n < NF; ++n)                                       \
                acc[m][n] = __builtin_amdgcn_mfma_f32_16x16x32_bf16(           \
                    af[m], bfr[n], acc[m][n], 0, 0, 0);                        \
    }

#pragma unroll 1
    for (int gr = 0; gr < 24; ++gr) {
        const int s0 = 3 * gr;

        // ---- group-top issues (land during this group's compute) ----
        if (gr < 23) {
#pragma unroll
            for (int q = 0; q < 3; ++q) {
                const int u = s0 + 3 + q;
                const int tu = u % 9, cu = (u / 9) * 32;
#pragma unroll
                for (int it = 0; it < BIT; ++it)
                    bstg[q][it] = *(const bf16x8*)(bptr[it] + (size_t)tu * 65536 + cu);
            }
        }
        if ((gr % 3) == 0) {
            const int cb = gr / 3;               // current chunk
            if (cb < 7) {
                const int co_ = (cb + 1) * 32;
#pragma unroll
                for (int it = 0; it < AIT; ++it)
                    astg[it] = *(const bf16x8*)(aptr[it] + co_);
            }
        }

        // ---- three compute steps ----
        DO_STEP(s0)
        DO_STEP(s0 + 1)
        DO_STEP(s0 + 2)

        // ---- group-end LDS writes ----
        if (gr < 23) {
#pragma unroll
            for (int q = 0; q < 3; ++q) {
                const int w = ((s0 + 3 + q) % 6) * BBUF;
#pragma unroll
                for (int it = 0; it < BIT; ++it)
                    *(bf16x8*)&s_b[w + boff[it]] = bstg[q][it];
            }
        }
        if ((gr % 3) == 2) {
            const int cw = gr / 3;               // chunk whose +1 we staged
            if (cw < 7) {
                const int dst = ((cw + 1) & 1) * ABUF;
#pragma unroll
                for (int it = 0; it < AIT; ++it)
                    *(bf16x8*)&s_a[dst + aoff[it]] = astg[it];
            }
        }
        __syncthreads();
    }
#undef DO_STEP

    // ---- epilogue: bias + relu -> bf16 planes (padded stride 844) ----
#pragma unroll
    for (int n = 0; n < NF; ++n) {
        const int co = wn * 64 + n * 16 + lc;
        const float sc = gamma[co] * rsqrtf(var[co] + BN_EPS);
        const float bias = beta[co] - mean[co] * sc;
#pragma unroll
        for (int m = 0; m < MF; ++m) {
            int pm = wm * 112 + m * 16 + lr * 4;
            int p = p0 + pm;
            f32x4 v = acc[m][n];
            float r0 = fmaxf(v.x + bias, 0.f);
            float r1 = fmaxf(v.y + bias, 0.f);
            float r2 = fmaxf(v.z + bias, 0.f);
            float r3 = fmaxf(v.w + bias, 0.f);
            unsigned short* op = outp + ((size_t)b * C + co) * 844 + p;
            if (p + 4 <= NPOS) {
                ushort4 pk;
                pk.x = f2bf(r0); pk.y = f2bf(r1); pk.z = f2bf(r2); pk.w = f2bf(r3);
                *(ushort4*)op = pk;
            } else {
                float rr[4] = {r0, r1, r2, r3};
#pragma unroll
                for (int i = 0; i < 4; ++i)
                    if (p + i < NPOS) op[i] = f2bf(rr[i]);
            }
        }
    }
}

// ---------------------------------------------------------------------------
// KERNEL CONV (small, 7x7 -> 5x5): B from global, A async-staged in LDS.
// ---------------------------------------------------------------------------
template<int HIN, int WOUT, int BPB, int BM, int BN_, int MF, int NF, bool OUT_BF16, int OSTRIDE>
__global__ __launch_bounds__(256, 3) void conv3_mfma(
    const unsigned short* __restrict__ in,
    const unsigned short* __restrict__ wt,
    const float* __restrict__ gamma, const float* __restrict__ beta,
    const float* __restrict__ mean, const float* __restrict__ var,
    void* __restrict__ outv)
{
    constexpr int WIN = HIN, HW = HIN * WIN;
    constexpr int NPOS = WOUT * WOUT;
    constexpr int PPB = BM / BPB;
    constexpr int NMT = (NPOS + PPB - 1) / PPB;
    constexpr int NR0 = (PPB - 1) / WOUT + 4;
    constexpr int NROWS = NR0 < HIN ? NR0 : HIN;
    constexpr int APIX = NROWS * WIN;
    constexpr int LDK = 40;
    constexpr int SLOTS_B = APIX * 4;
    constexpr int SLOTS = BPB * SLOTS_B;
    constexpr int ITERS = (SLOTS + 255) / 256;

    __shared__ __align__(16) short s_a[BPB * APIX * LDK];

    const int t = threadIdx.x;
    const int lane = t & 63, wave = t >> 6;
    const int wm = wave >> 1, wn = wave & 1;
    const int lr = lane >> 4, lc = lane & 15;

    const int mt = blockIdx.x % NMT, nt = blockIdx.x / NMT;
    const int p0 = mt * PPB, n0 = nt * BN_;
    const int b0 = blockIdx.y * BPB;
    const int y0 = p0 / WOUT;
    const int R = (HIN - y0) < NROWS ? (HIN - y0) : NROWS;
    const int npix = R * WIN;

    int arow[MF];
#pragma unroll
    for (int m = 0; m < MF; ++m) {
        int pm = wm * MF * 16 + m * 16 + lc;
        int bb = pm / PPB;
        int p = p0 + (pm % PPB);
        p = p < NPOS ? p : NPOS - 1;
        int y = p / WOUT, x = p % WOUT;
        arow[m] = (bb * APIX + (y - y0) * WIN + x) * LDK;
    }

    f32x4 acc[MF][NF];
#pragma unroll
    for (int m = 0; m < MF; ++m)
#pragma unroll
        for (int n = 0; n < NF; ++n) acc[m][n] = f32x4{0.f, 0.f, 0.f, 0.f};

    int sbb[ITERS], spx[ITERS], ssl[ITERS];
#pragma unroll
    for (int it = 0; it < ITERS; ++it) {
        int i = t + it * 256;
        int ii = i < SLOTS ? i : 0;
        int bb = (BPB == 1) ? 0 : (ii / SLOTS_B);
        int r = ii - bb * SLOTS_B;
        int px = r >> 2;
        sbb[it] = bb; spx[it] = px < npix ? px : 0; ssl[it] = r & 3;
    }

    const unsigned short* wb = wt + (size_t)(n0 + wn * (NF * 16) + lc) * C + lr * 8;

#define LOAD_STG(c0_)                                                          \
    _Pragma("unroll")                                                          \
    for (int it = 0; it < ITERS; ++it) {                                       \
        const unsigned short* sp =                                             \
            in + ((size_t)(b0 + sbb[it]) * HW + (size_t)(y0 * WIN + spx[it])) * C \
               + (c0_) + ssl[it] * 8;                                          \
        stg[it] = *(const bf16x8*)sp;                                          \
    }

#define WRITE_STG()                                                            \
    _Pragma("unroll")                                                          \
    for (int it = 0; it < ITERS; ++it)                                         \
        *(bf16x8*)&s_a[(sbb[it] * APIX + spx[it]) * LDK + ssl[it] * 8] = stg[it];

    {
        bf16x8 stg[ITERS];
        LOAD_STG(0)
        WRITE_STG()
    }

#pragma unroll 1
    for (int ch = 0; ch < 8; ++ch) {
        const int c0 = ch * 32;
        __syncthreads();

        bf16x8 stg[ITERS];
        if (ch < 7) { LOAD_STG(c0 + 32) }

        bf16x8 bcur[NF], bnxt[NF];
#pragma unroll
        for (int n = 0; n < NF; ++n)
            bnxt[n] = *(const bf16x8*)&wb[0 * (size_t)(C * C) + n * (16 * C) + c0];

#pragma unroll
        for (int tap = 0; tap < 9; ++tap) {
            const int dy = tap / 3, dx = tap % 3;
#pragma unroll
            for (int n = 0; n < NF; ++n) bcur[n] = bnxt[n];
            if (tap < 8) {
#pragma unroll
                for (int n = 0; n < NF; ++n)
                    bnxt[n] = *(const bf16x8*)&wb[(size_t)(tap + 1) * (C * C) + n * (16 * C) + c0];
            }
            bf16x8 af[MF];
#pragma unroll
            for (int m = 0; m < MF; ++m)
                af[m] = *(const bf16x8*)&s_a[arow[m] + (dy * WIN + dx) * LDK + lr * 8];
#pragma unroll
            for (int m = 0; m < MF; ++m)
#pragma unroll
                for (int n = 0; n < NF; ++n)
                    acc[m][n] = __builtin_amdgcn_mfma_f32_16x16x32_bf16(
                        af[m], bcur[n], acc[m][n], 0, 0, 0);
        }

        __syncthreads();
        if (ch < 7) { WRITE_STG() }
    }
#undef LOAD_STG
#undef WRITE_STG

#pragma unroll
    for (int n = 0; n < NF; ++n) {
        const int co = n0 + wn * NF * 16 + n * 16 + lc;
        const float sc = gamma[co] * rsqrtf(var[co] + BN_EPS);
        const float bias = beta[co] - mean[co] * sc;
#pragma unroll
        for (int m = 0; m < MF; ++m) {
            int pm = wm * MF * 16 + m * 16 + lr * 4;
            int bb = pm / PPB;
            int p = p0 + (pm % PPB);
            int b = b0 + bb;
            f32x4 v = acc[m][n];
            float r0 = fmaxf(v.x + bias, 0.f);
            float r1 = fmaxf(v.y + bias, 0.f);
            float r2 = fmaxf(v.z + bias, 0.f);
            float r3 = fmaxf(v.w + bias, 0.f);
            if (OUT_BF16) {
                unsigned short* op = (unsigned short*)outv + ((size_t)b * C + co) * OSTRIDE + p;
                if (p + 4 <= NPOS) {
                    ushort4 pk;
                    pk.x = f2bf(r0); pk.y = f2bf(r1); pk.z = f2bf(r2); pk.w = f2bf(r3);
                    *(ushort4*)op = pk;
                } else {
                    float rr[4] = {r0, r1, r2, r3};
#pragma unroll
                    for (int i = 0; i < 4; ++i)
                        if (p + i < NPOS) op[i] = f2bf(rr[i]);
                }
            } else {
                float* op = (float*)outv + ((size_t)b * C + co) * OSTRIDE + p;
                float rr[4] = {r0, r1, r2, r3};
#pragma unroll
                for (int i = 0; i < 4; ++i)
                    if (p + i < NPOS) op[i] = rr[i];
            }
        }
    }
}

// Depthwise 5x5 valid xcorr: s bf16 [g,C,844], k f32 [g,C,28] -> out f32 [g,C,625].
__global__ __launch_bounds__(256) void xcorr_dw(
    const unsigned short* __restrict__ s, const float* __restrict__ k,
    float* __restrict__ out)
{
    const int bc = blockIdx.x;
    const unsigned short* sp = s + (size_t)bc * 844;
    const float* kp = k + (size_t)bc * 28;
    float* op = out + (size_t)bc * 625;

    __shared__ float s_s[844];
    __shared__ float s_k[25];
    const int t = threadIdx.x;
    if (t < 211) {
        ushort4 v = *(const ushort4*)(sp + 4 * t);
        s_s[4 * t + 0] = bf2f(v.x);
        s_s[4 * t + 1] = bf2f(v.y);
        s_s[4 * t + 2] = bf2f(v.z);
        s_s[4 * t + 3] = bf2f(v.w);
    }
    if (t < 25) s_k[t] = kp[t];
    __syncthreads();

    float kk[25];
#pragma unroll
    for (int i = 0; i < 25; ++i) kk[i] = s_k[i];

#pragma unroll
    for (int j = 0; j < 3; ++j) {
        int pos = t + j * 256;
        if (pos < 625) {
            int y = pos / 25, x = pos - y * 25;
            float a = 0.f;
#pragma unroll
            for (int dy = 0; dy < 5; ++dy)
#pragma unroll
                for (int dx = 0; dx < 5; ++dx)
                    a += s_s[(y + dy) * 29 + x + dx] * kk[dy * 5 + dx];
            op[pos] = a;
        }
    }
}

extern "C" void kernel_launch(void* const* d_in, const int* in_sizes, int n_in,
                              void* d_out, int out_size, void* d_ws, size_t ws_size,
                              hipStream_t stream) {
    const float* kin = (const float*)d_in[0];   // [128,256,7,7]
    const float* sin_ = (const float*)d_in[1];  // [128,256,31,31]
    const float* wk = (const float*)d_in[2];
    const float* bkg = (const float*)d_in[3];
    const float* bkb = (const float*)d_in[4];
    const float* bkm = (const float*)d_in[5];
    const float* bkv = (const float*)d_in[6];
    const float* ws_ = (const float*)d_in[7];
    const float* bsg = (const float*)d_in[8];
    const float* bsb = (const float*)d_in[9];
    const float* bsm = (const float*)d_in[10];
    const float* bsv = (const float*)d_in[11];
    float* out = (float*)d_out;

    char* base = (char*)d_ws;
    unsigned short* wkt = (unsigned short*)base;               // 1,179,648 B
    unsigned short* wst = wkt + (size_t)9 * C * C;
    char* gbase = base + 2359296;

    const size_t perb_is = (size_t)961 * C * 2;  // 492032
    const size_t perb_ik = (size_t)49 * C * 2;   // 25088
    const size_t perb_sb = (size_t)844 * C * 2;  // 432128
    const size_t perb_kb = (size_t)28 * C * 4;   // 28672
    const size_t perb = perb_is + perb_ik + perb_sb + perb_kb; // 977920

    int G = (int)((ws_size - 2359296) / perb);
    if (G > 128) G = 128;
    G &= ~1;
    if (G < 2) G = 2;

    unsigned short* ips  = (unsigned short*)gbase;
    unsigned short* ipk  = (unsigned short*)(gbase + (size_t)G * perb_is);
    unsigned short* sbuf = (unsigned short*)(gbase + (size_t)G * (perb_is + perb_ik));
    float*          kbuf = (float*)(gbase + (size_t)G * (perb_is + perb_ik + perb_sb));

    wprep<<<C, 256, 0, stream>>>(wk, bkg, bkv, wkt);
    wprep<<<C, 256, 0, stream>>>(ws_, bsg, bsv, wst);

    for (int g0 = 0; g0 < 128; g0 += G) {
        const int g = (128 - g0) < G ? (128 - g0) : G;

        nchw_to_pc<961><<<dim3(16, 4, g), 256, 0, stream>>>(
            sin_ + (size_t)g0 * C * 961, ips);
        nchw_to_pc<49><<<dim3(1, 4, g), 256, 0, stream>>>(
            kin + (size_t)g0 * C * 49, ipk);

        // kernel conv: 7x7 -> 5x5. BPB=2, BM=64, BN=64 (4 N-tiles -> 256 blocks).
        conv3_mfma<7, 5, 2, 64, 64, 2, 2, false, 28>
            <<<dim3(4, g / 2), 256, 0, stream>>>(ipk, wkt, bkg, bkb, bkm, bkv, kbuf);

        // search conv v6: 3-step barrier groups, 6x B-buffer (LDK=36).
        sconv_mfma<<<dim3(4, g), 512, 0, stream>>>(
            ips, wst, bsg, bsb, bsm, bsv, sbuf);

        xcorr_dw<<<(unsigned)g * C, 256, 0, stream>>>(sbuf, kbuf, out + (size_t)g0 * C * 625);
    }
}

// Round 11
// 288.733 us; speedup vs baseline: 1.2090x; 1.0533x over previous
//
#include <hip/hip_runtime.h>
#include <hip/hip_bf16.h>

#define BN_EPS 1e-5f
constexpr int C = 256;

typedef __attribute__((ext_vector_type(8))) short bf16x8;
typedef __attribute__((ext_vector_type(4))) float f32x4;

static __device__ __forceinline__ unsigned short f2bf(float f) {
    __hip_bfloat16 h = __float2bfloat16(f);
    return *reinterpret_cast<unsigned short*>(&h);
}
static __device__ __forceinline__ float bf2f(unsigned short u) {
    unsigned int v = ((unsigned int)u) << 16;
    return __uint_as_float(v);
}

// ---------------------------------------------------------------------------
// L1 PREP (fused): wprep(kernel) + wprep(search) + kernel-input transpose.
// blocks [0,nw/2): wprep wk->wkt ; [nw/2,nw): wprep ws->wst ;
// [nw, nw+4g): nchw_to_pc<49> kin->ipk.
// ---------------------------------------------------------------------------
__global__ __launch_bounds__(256) void prep_fused(
    const float* __restrict__ wk, const float* __restrict__ bkg, const float* __restrict__ bkv,
    unsigned short* __restrict__ wkt,
    const float* __restrict__ ws, const float* __restrict__ bsg, const float* __restrict__ bsv,
    unsigned short* __restrict__ wst,
    const float* __restrict__ kin, unsigned short* __restrict__ ipk,
    int nw)
{
    __shared__ float s_t[64][65];
    const int bid = blockIdx.x;
    const int t = threadIdx.x;

    if (bid < nw) {
        // weight prep: fold BN scale, transpose [N][C][9] f32 -> [9][N][C] bf16
        const bool isk = bid < (nw >> 1);
        const int n = isk ? bid : bid - (nw >> 1);
        const float* w = isk ? wk : ws;
        const float* g = isk ? bkg : bsg;
        const float* v = isk ? bkv : bsv;
        unsigned short* wt = isk ? wkt : wst;
        const float scale = g[n] * rsqrtf(v[n] + BN_EPS);
        const float* wp = w + ((size_t)n * C + t) * 9;
#pragma unroll
        for (int k = 0; k < 9; ++k)
            wt[((size_t)k * C + n) * C + t] = f2bf(wp[k] * scale);
        return;
    }

    // kernel-input transpose: fp32 [g][C][49] -> bf16 [g][49][256]
    const int idx = bid - nw;
    const int b = idx >> 2, c0 = (idx & 3) * 64;
    constexpr int HW = 49;
    const float* ip = kin + ((size_t)b * C + c0) * HW;

#pragma unroll
    for (int it = 0; it < 4; ++it) {
        int i = t + it * 256;
        int cl = i >> 4, q = i & 15;
#pragma unroll
        for (int j = 0; j < 4; ++j) {
            int p = q * 4 + j;
            s_t[cl][p] = (p < HW) ? ip[(size_t)cl * HW + p] : 0.f;
        }
    }
    __syncthreads();

    unsigned short* op = ipk + (size_t)b * HW * C + c0;
#pragma unroll
    for (int it = 0; it < 2; ++it) {
        int i = t + it * 256;
        int pl = i >> 3, gq = i & 7;
        if (pl < HW) {
            bf16x8 pk;
#pragma unroll
            for (int u = 0; u < 8; ++u)
                pk[u] = (short)f2bf(s_t[gq * 8 + u][pl]);
            *(bf16x8*)&op[(size_t)pl * C + gq * 8] = pk;
        }
    }
}

// ---------------------------------------------------------------------------
// L2 (fused): kconv (first nkc blocks) + search-input transpose (rest).
// kconv: 7x7 -> 5x5 implicit-GEMM bf16 MFMA, B from global, A staged in LDS.
//   decode: nt = bid&3 (N-tile of 64), bp = bid>>2 (batch pair).
// transpose: fp32 [g][C][961] -> bf16 [g][961][256].
// ---------------------------------------------------------------------------
__global__ __launch_bounds__(256) void l2_fused(
    const float* __restrict__ sin_, unsigned short* __restrict__ ips,
    const unsigned short* __restrict__ ipk, const unsigned short* __restrict__ wkt,
    const float* __restrict__ bkg, const float* __restrict__ bkb,
    const float* __restrict__ bkm, const float* __restrict__ bkv,
    float* __restrict__ kbuf, int nkc)
{
    __shared__ __align__(16) char smem[16640];
    const int bid = blockIdx.x;
    const int t = threadIdx.x;

    if (bid < nkc) {
        // ---------------- kconv ----------------
        constexpr int WIN = 7, HW = 49, WOUT = 5, NPOS = 25;
        constexpr int BPB = 2, PPB = 32, MF = 2, NF = 2;
        constexpr int APIX = 49, LDK = 40;
        constexpr int SLOTS_B = APIX * 4, SLOTS = BPB * SLOTS_B;  // 392
        constexpr int ITERS = 2;

        short* s_a = (short*)smem;   // 2*49*40*2 = 7840 B

        const int lane = t & 63, wave = t >> 6;
        const int wm = wave >> 1, wn = wave & 1;
        const int lr = lane >> 4, lc = lane & 15;

        const int n0 = (bid & 3) * 64;
        const int b0 = (bid >> 2) * 2;

        int arow[MF];
#pragma unroll
        for (int m = 0; m < MF; ++m) {
            int pm = wm * 32 + m * 16 + lc;
            int bb = pm / PPB;
            int p = pm % PPB;
            p = p < NPOS ? p : NPOS - 1;
            int y = p / WOUT, x = p % WOUT;
            arow[m] = (bb * APIX + y * WIN + x) * LDK;
        }

        f32x4 acc[MF][NF];
#pragma unroll
        for (int m = 0; m < MF; ++m)
#pragma unroll
            for (int n = 0; n < NF; ++n) acc[m][n] = f32x4{0.f, 0.f, 0.f, 0.f};

        int sbb[ITERS], spx[ITERS], ssl[ITERS];
#pragma unroll
        for (int it = 0; it < ITERS; ++it) {
            int i = t + it * 256;
            int ii = i < SLOTS ? i : 0;
            int bb = ii / SLOTS_B;
            int r = ii - bb * SLOTS_B;
            sbb[it] = bb; spx[it] = r >> 2; ssl[it] = r & 3;
        }

        const unsigned short* wb = wkt + (size_t)(n0 + wn * 32 + lc) * C + lr * 8;

#define K_LOAD(c0_)                                                            \
        _Pragma("unroll")                                                      \
        for (int it = 0; it < ITERS; ++it) {                                   \
            const unsigned short* sp =                                         \
                ipk + ((size_t)(b0 + sbb[it]) * HW + spx[it]) * C + (c0_) + ssl[it] * 8; \
            stg[it] = *(const bf16x8*)sp;                                      \
        }
#define K_WRITE()                                                              \
        _Pragma("unroll")                                                      \
        for (int it = 0; it < ITERS; ++it)                                     \
            *(bf16x8*)&s_a[(sbb[it] * APIX + spx[it]) * LDK + ssl[it] * 8] = stg[it];

        {
            bf16x8 stg[ITERS];
            K_LOAD(0)
            K_WRITE()
        }

#pragma unroll 1
        for (int ch = 0; ch < 8; ++ch) {
            const int c0 = ch * 32;
            __syncthreads();

            bf16x8 stg[ITERS];
            if (ch < 7) { K_LOAD(c0 + 32) }

            bf16x8 bcur[NF], bnxt[NF];
#pragma unroll
            for (int n = 0; n < NF; ++n)
                bnxt[n] = *(const bf16x8*)&wb[(size_t)0 * (C * C) + n * (16 * C) + c0];

#pragma unroll
            for (int tap = 0; tap < 9; ++tap) {
                const int dy = tap / 3, dx = tap % 3;
#pragma unroll
                for (int n = 0; n < NF; ++n) bcur[n] = bnxt[n];
                if (tap < 8) {
#pragma unroll
                    for (int n = 0; n < NF; ++n)
                        bnxt[n] = *(const bf16x8*)&wb[(size_t)(tap + 1) * (C * C) + n * (16 * C) + c0];
                }
                bf16x8 af[MF];
#pragma unroll
                for (int m = 0; m < MF; ++m)
                    af[m] = *(const bf16x8*)&s_a[arow[m] + (dy * WIN + dx) * LDK + lr * 8];
#pragma unroll
                for (int m = 0; m < MF; ++m)
#pragma unroll
                    for (int n = 0; n < NF; ++n)
                        acc[m][n] = __builtin_amdgcn_mfma_f32_16x16x32_bf16(
                            af[m], bcur[n], acc[m][n], 0, 0, 0);
            }

            __syncthreads();
            if (ch < 7) { K_WRITE() }
        }
#undef K_LOAD
#undef K_WRITE

#pragma unroll
        for (int n = 0; n < NF; ++n) {
            const int co = n0 + wn * 32 + n * 16 + lc;
            const float sc = bkg[co] * rsqrtf(bkv[co] + BN_EPS);
            const float bias = bkb[co] - bkm[co] * sc;
#pragma unroll
            for (int m = 0; m < MF; ++m) {
                int pm = wm * 32 + m * 16 + lr * 4;
                int bb = pm / PPB;
                int p = pm % PPB;
                int b = b0 + bb;
                f32x4 v = acc[m][n];
                float rr[4] = {fmaxf(v.x + bias, 0.f), fmaxf(v.y + bias, 0.f),
                               fmaxf(v.z + bias, 0.f), fmaxf(v.w + bias, 0.f)};
                float* op = kbuf + ((size_t)b * C + co) * 28 + p;
#pragma unroll
                for (int i = 0; i < 4; ++i)
                    if (p + i < NPOS) op[i] = rr[i];
            }
        }
        return;
    }

    // ---------------- search-input transpose ----------------
    {
        constexpr int HW = 961;
        float (*s_t)[65] = (float(*)[65])smem;
        const int idx = bid - nkc;
        const int px0 = (idx & 15) * 64;
        const int c0 = ((idx >> 4) & 3) * 64;
        const int b = idx >> 6;
        const float* ip = sin_ + ((size_t)b * C + c0) * HW;

#pragma unroll
        for (int it = 0; it < 4; ++it) {
            int i = t + it * 256;
            int cl = i >> 4, q = i & 15;
#pragma unroll
            for (int j = 0; j < 4; ++j) {
                int p = px0 + q * 4 + j;
                s_t[cl][q * 4 + j] = (p < HW) ? ip[(size_t)cl * HW + p] : 0.f;
            }
        }
        __syncthreads();

        unsigned short* op = ips + (size_t)b * HW * C + (size_t)px0 * C + c0;
#pragma unroll
        for (int it = 0; it < 2; ++it) {
            int i = t + it * 256;
            int pl = i >> 3, gq = i & 7;
            if (px0 + pl < HW) {
                bf16x8 pk;
#pragma unroll
                for (int u = 0; u < 8; ++u)
                    pk[u] = (short)f2bf(s_t[gq * 8 + u][pl]);
                *(bf16x8*)&op[(size_t)pl * C + gq * 8] = pk;
            }
        }
    }
}

// ---------------------------------------------------------------------------
// SEARCH CONV v7 (r8 schedule + LDK=36 + setprio):
// 31x31 -> 29x29 implicit-GEMM bf16 MFMA. A and B both staged in LDS.
// Block: 512 thr = 8 waves (2 wm x 4 wn). BM=224, BN=256, wave tile 112x64.
// K-steps s = 0..71 (chunk = s/9, tap = s%9). B: 4 buffers, barrier every TWO
// steps (read {s0%4,s1%4}, write {(s0+2)%4,(s1+2)%4} — disjoint). B loads for
// pair i+1 issued at top of pair i. A: 2 buffers; loads issued at the
// chunk-start pair, written at the s%9==7 pair.
// ---------------------------------------------------------------------------
__global__ __launch_bounds__(512, 2) void sconv_mfma(
    const unsigned short* __restrict__ in,   // [g][961][256] bf16
    const unsigned short* __restrict__ wt,   // [9][256][256] bf16
    const float* __restrict__ gamma, const float* __restrict__ beta,
    const float* __restrict__ mean, const float* __restrict__ var,
    unsigned short* __restrict__ outp)       // [g][256][844] bf16
{
    constexpr int WOUT = 29, NPOS = 841;
    constexpr int BM = 224, MF = 7, NF = 4;
    constexpr int LDK = 36;                  // 32 ch + 4 pad (72B rows, conflict-free b128)
    constexpr int ROWS = 11;
    constexpr int APIX = ROWS * 31;          // 341
    constexpr int ABUF = APIX * LDK;         // 12276 shorts
    constexpr int BBUF = 256 * LDK;          // 9216 shorts
    constexpr int AIT = 3;                   // ceil(341*4 / 512)
    constexpr int BIT = 2;                   // 256*4 / 512

    __shared__ __align__(16) short s_a[2 * ABUF];   // 49,104 B
    __shared__ __align__(16) short s_b[4 * BBUF];   // 73,728 B (total 122,832)

    const int t = threadIdx.x;
    const int lane = t & 63, wave = t >> 6;
    const int wm = wave >> 2, wn = wave & 3;
    const int lr = lane >> 4, lc = lane & 15;

    const int p0 = blockIdx.x * BM;          // 0,224,448,672
    const int b  = blockIdx.y;
    const int y0 = p0 / WOUT;
    const int R  = min(ROWS, 31 - y0);
    const int npix = R * 31;

    const unsigned short* in_b = in + (size_t)b * (961 * 256);

    int arow[MF];
#pragma unroll
    for (int m = 0; m < MF; ++m) {
        int pm = wm * 112 + m * 16 + lc;
        int p = p0 + pm; p = p < NPOS ? p : NPOS - 1;
        int y = p / WOUT, x = p - y * WOUT;
        arow[m] = ((y - y0) * 31 + x) * LDK + lr * 8;
    }

    const unsigned short* aptr[AIT]; int aoff[AIT];
#pragma unroll
    for (int it = 0; it < AIT; ++it) {
        int i = t + it * 512;
        int px = i >> 2, sl = i & 3;
        px = px < npix ? px : 0;             // idempotent dup of slot 0
        aptr[it] = in_b + (size_t)(y0 * 31 + px) * 256 + sl * 8;
        aoff[it] = px * LDK + sl * 8;
    }
    const unsigned short* bptr[BIT]; int boff[BIT];
#pragma unroll
    for (int it = 0; it < BIT; ++it) {
        int i = t + it * 512;
        int n = i >> 2, sl = i & 3;
        bptr[it] = wt + (size_t)n * 256 + sl * 8;
        boff[it] = n * LDK + sl * 8;
    }

    f32x4 acc[MF][NF];
#pragma unroll
    for (int m = 0; m < MF; ++m)
#pragma unroll
        for (int n = 0; n < NF; ++n) acc[m][n] = f32x4{0.f, 0.f, 0.f, 0.f};

    bf16x8 bstg0[BIT], bstg1[BIT], astg[AIT];

    // prologue: stage B steps 0,1 and A chunk 0
#pragma unroll
    for (int it = 0; it < BIT; ++it) bstg0[it] = *(const bf16x8*)(bptr[it]);
#pragma unroll
    for (int it = 0; it < BIT; ++it) bstg1[it] = *(const bf16x8*)(bptr[it] + 65536);
#pragma unroll
    for (int it = 0; it < AIT; ++it) astg[it] = *(const bf16x8*)(aptr[it]);
#pragma unroll
    for (int it = 0; it < BIT; ++it) *(bf16x8*)&s_b[boff[it]] = bstg0[it];
#pragma unroll
    for (int it = 0; it < BIT; ++it) *(bf16x8*)&s_b[BBUF + boff[it]] = bstg1[it];
#pragma unroll
    for (int it = 0; it < AIT; ++it) *(bf16x8*)&s_a[aoff[it]] = astg[it];
    __syncthreads();

#define DO_STEP(S)                                                             \
    {                                                                          \
        const int tap_ = (S) % 9;                                              \
        const int dt_ = (tap_ / 3) * 31 + (tap_ % 3);                          \
        const int ab_ = (((S) / 9) & 1) * ABUF;                                \
        const int bb_ = ((S) & 3) * BBUF;                                      \
        bf16x8 bfr[NF], af[MF];                                                \
        _Pragma("unroll")                                                      \
        for (int n = 0; n < NF; ++n)                                           \
            bfr[n] = *(const bf16x8*)&s_b[bb_ + (wn * 64 + n * 16 + lc) * LDK + lr * 8]; \
        _Pragma("unroll")                                                      \
        for (int m = 0; m < MF; ++m)                                           \
            af[m] = *(const bf16x8*)&s_a[ab_ + arow[m] + dt_ * LDK];           \
        __builtin_amdgcn_s_setprio(1);                                         \
        _Pragma("unroll")                                                      \
        for (int m = 0; m < MF; ++m)                                           \
            _Pragma("unroll")                                                  \
            for (int n = 0; n < NF; ++n)                                       \
                acc[m][n] = __builtin_amdgcn_mfma_f32_16x16x32_bf16(           \
                    af[m], bfr[n], acc[m][n], 0, 0, 0);                        \
        __builtin_amdgcn_s_setprio(0);                                         \
    }

#pragma unroll 1
    for (int pr = 0; pr < 36; ++pr) {
        const int s0 = 2 * pr, s1 = s0 + 1;

        if (pr < 35) {
            const int u0 = s0 + 2, u1 = s1 + 2;
            const int t0 = u0 % 9, c0_ = (u0 / 9) * 32;
            const int t1 = u1 % 9, c1_ = (u1 / 9) * 32;
#pragma unroll
            for (int it = 0; it < BIT; ++it)
                bstg0[it] = *(const bf16x8*)(bptr[it] + (size_t)t0 * 65536 + c0_);
#pragma unroll
            for (int it = 0; it < BIT; ++it)
                bstg1[it] = *(const bf16x8*)(bptr[it] + (size_t)t1 * 65536 + c1_);
        }
        {
            const int cb = (s0 % 9 == 0) ? s0 / 9 : ((s1 % 9 == 0) ? s1 / 9 : -1);
            if (cb >= 0 && cb < 7) {
                const int co_ = (cb + 1) * 32;
#pragma unroll
                for (int it = 0; it < AIT; ++it)
                    astg[it] = *(const bf16x8*)(aptr[it] + co_);
            }
        }

        DO_STEP(s0)
        DO_STEP(s1)

        if (pr < 35) {
            const int w0 = ((s0 + 2) & 3) * BBUF, w1 = ((s1 + 2) & 3) * BBUF;
#pragma unroll
            for (int it = 0; it < BIT; ++it)
                *(bf16x8*)&s_b[w0 + boff[it]] = bstg0[it];
#pragma unroll
            for (int it = 0; it < BIT; ++it)
                *(bf16x8*)&s_b[w1 + boff[it]] = bstg1[it];
        }
        {
            const int cw = (s0 % 9 == 7) ? s0 / 9 : ((s1 % 9 == 7) ? s1 / 9 : -1);
            if (cw >= 0 && cw < 7) {
                const int dst = ((cw & 1) ^ 1) * ABUF;
#pragma unroll
                for (int it = 0; it < AIT; ++it)
                    *(bf16x8*)&s_a[dst + aoff[it]] = astg[it];
            }
        }
        __syncthreads();
    }
#undef DO_STEP

    // epilogue: bias + relu -> bf16 planes (padded stride 844)
#pragma unroll
    for (int n = 0; n < NF; ++n) {
        const int co = wn * 64 + n * 16 + lc;
        const float sc = gamma[co] * rsqrtf(var[co] + BN_EPS);
        const float bias = beta[co] - mean[co] * sc;
#pragma unroll
        for (int m = 0; m < MF; ++m) {
            int pm = wm * 112 + m * 16 + lr * 4;
            int p = p0 + pm;
            f32x4 v = acc[m][n];
            float r0 = fmaxf(v.x + bias, 0.f);
            float r1 = fmaxf(v.y + bias, 0.f);
            float r2 = fmaxf(v.z + bias, 0.f);
            float r3 = fmaxf(v.w + bias, 0.f);
            unsigned short* op = outp + ((size_t)b * C + co) * 844 + p;
            if (p + 4 <= NPOS) {
                ushort4 pk;
                pk.x = f2bf(r0); pk.y = f2bf(r1); pk.z = f2bf(r2); pk.w = f2bf(r3);
                *(ushort4*)op = pk;
            } else {
                float rr[4] = {r0, r1, r2, r3};
#pragma unroll
                for (int i = 0; i < 4; ++i)
                    if (p + i < NPOS) op[i] = f2bf(rr[i]);
            }
        }
    }
}

// Depthwise 5x5 valid xcorr: s bf16 [g,C,844], k f32 [g,C,28] -> out f32 [g,C,625].
__global__ __launch_bounds__(256) void xcorr_dw(
    const unsigned short* __restrict__ s, const float* __restrict__ k,
    float* __restrict__ out)
{
    const int bc = blockIdx.x;
    const unsigned short* sp = s + (size_t)bc * 844;
    const float* kp = k + (size_t)bc * 28;
    float* op = out + (size_t)bc * 625;

    __shared__ float s_s[844];
    __shared__ float s_k[25];
    const int t = threadIdx.x;
    if (t < 211) {
        ushort4 v = *(const ushort4*)(sp + 4 * t);
        s_s[4 * t + 0] = bf2f(v.x);
        s_s[4 * t + 1] = bf2f(v.y);
        s_s[4 * t + 2] = bf2f(v.z);
        s_s[4 * t + 3] = bf2f(v.w);
    }
    if (t < 25) s_k[t] = kp[t];
    __syncthreads();

    float kk[25];
#pragma unroll
    for (int i = 0; i < 25; ++i) kk[i] = s_k[i];

#pragma unroll
    for (int j = 0; j < 3; ++j) {
        int pos = t + j * 256;
        if (pos < 625) {
            int y = pos / 25, x = pos - y * 25;
            float a = 0.f;
#pragma unroll
            for (int dy = 0; dy < 5; ++dy)
#pragma unroll
                for (int dx = 0; dx < 5; ++dx)
                    a += s_s[(y + dy) * 29 + x + dx] * kk[dy * 5 + dx];
            op[pos] = a;
        }
    }
}

extern "C" void kernel_launch(void* const* d_in, const int* in_sizes, int n_in,
                              void* d_out, int out_size, void* d_ws, size_t ws_size,
                              hipStream_t stream) {
    const float* kin = (const float*)d_in[0];   // [128,256,7,7]
    const float* sin_ = (const float*)d_in[1];  // [128,256,31,31]
    const float* wk = (const float*)d_in[2];
    const float* bkg = (const float*)d_in[3];
    const float* bkb = (const float*)d_in[4];
    const float* bkm = (const float*)d_in[5];
    const float* bkv = (const float*)d_in[6];
    const float* ws_ = (const float*)d_in[7];
    const float* bsg = (const float*)d_in[8];
    const float* bsb = (const float*)d_in[9];
    const float* bsm = (const float*)d_in[10];
    const float* bsv = (const float*)d_in[11];
    float* out = (float*)d_out;

    char* base = (char*)d_ws;
    unsigned short* wkt = (unsigned short*)base;               // 1,179,648 B
    unsigned short* wst = wkt + (size_t)9 * C * C;
    char* gbase = base + 2359296;

    const size_t perb_is = (size_t)961 * C * 2;  // 492032
    const size_t perb_ik = (size_t)49 * C * 2;   // 25088
    const size_t perb_sb = (size_t)844 * C * 2;  // 432128
    const size_t perb_kb = (size_t)28 * C * 4;   // 28672
    const size_t perb = perb_is + perb_ik + perb_sb + perb_kb; // 977920

    int G = (int)((ws_size - 2359296) / perb);
    if (G > 128) G = 128;
    G &= ~1;
    if (G < 2) G = 2;

    unsigned short* ips  = (unsigned short*)gbase;
    unsigned short* ipk  = (unsigned short*)(gbase + (size_t)G * perb_is);
    unsigned short* sbuf = (unsigned short*)(gbase + (size_t)G * (perb_is + perb_ik));
    float*          kbuf = (float*)(gbase + (size_t)G * (perb_is + perb_ik + perb_sb));

    for (int g0 = 0; g0 < 128; g0 += G) {
        const int g = (128 - g0) < G ? (128 - g0) : G;
        const int nw = (g0 == 0) ? 512 : 0;     // wprep blocks only first pass

        // L1: wprep x2 + kernel transpose
        prep_fused<<<nw + 4 * g, 256, 0, stream>>>(
            wk, bkg, bkv, wkt, ws_, bsg, bsv, wst,
            kin + (size_t)g0 * C * 49, ipk, nw);

        // L2: kconv (first 2g blocks) + search transpose (64g blocks)
        const int nkc = 2 * g;
        l2_fused<<<nkc + 64 * g, 256, 0, stream>>>(
            sin_ + (size_t)g0 * C * 961, ips, ipk, wkt,
            bkg, bkb, bkm, bkv, kbuf, nkc);

        // L3: search conv v7
        sconv_mfma<<<dim3(4, g), 512, 0, stream>>>(
            ips, wst, bsg, bsb, bsm, bsv, sbuf);

        // L4: depthwise xcorr
        xcorr_dw<<<(unsigned)g * C, 256, 0, stream>>>(
            sbuf, kbuf, out + (size_t)g0 * C * 625);
    }
}

// Round 12
// 288.370 us; speedup vs baseline: 1.2105x; 1.0013x over previous
//
#include <hip/hip_runtime.h>
#include <hip/hip_bf16.h>

#define BN_EPS 1e-5f
constexpr int C = 256;

typedef __attribute__((ext_vector_type(8))) short bf16x8;
typedef __attribute__((ext_vector_type(4))) float f32x4;

static __device__ __forceinline__ unsigned short f2bf(float f) {
    __hip_bfloat16 h = __float2bfloat16(f);
    return *reinterpret_cast<unsigned short*>(&h);
}
static __device__ __forceinline__ float bf2f(unsigned short u) {
    unsigned int v = ((unsigned int)u) << 16;
    return __uint_as_float(v);
}

// ---------------------------------------------------------------------------
// L1 PREP (fused): wprep(kernel) + wprep(search) + kernel-input transpose.
// ---------------------------------------------------------------------------
__global__ __launch_bounds__(256) void prep_fused(
    const float* __restrict__ wk, const float* __restrict__ bkg, const float* __restrict__ bkv,
    unsigned short* __restrict__ wkt,
    const float* __restrict__ ws, const float* __restrict__ bsg, const float* __restrict__ bsv,
    unsigned short* __restrict__ wst,
    const float* __restrict__ kin, unsigned short* __restrict__ ipk,
    int nw)
{
    __shared__ float s_t[64][65];
    const int bid = blockIdx.x;
    const int t = threadIdx.x;

    if (bid < nw) {
        const bool isk = bid < (nw >> 1);
        const int n = isk ? bid : bid - (nw >> 1);
        const float* w = isk ? wk : ws;
        const float* g = isk ? bkg : bsg;
        const float* v = isk ? bkv : bsv;
        unsigned short* wt = isk ? wkt : wst;
        const float scale = g[n] * rsqrtf(v[n] + BN_EPS);
        const float* wp = w + ((size_t)n * C + t) * 9;
#pragma unroll
        for (int k = 0; k < 9; ++k)
            wt[((size_t)k * C + n) * C + t] = f2bf(wp[k] * scale);
        return;
    }

    const int idx = bid - nw;
    const int b = idx >> 2, c0 = (idx & 3) * 64;
    constexpr int HW = 49;
    const float* ip = kin + ((size_t)b * C + c0) * HW;

#pragma unroll
    for (int it = 0; it < 4; ++it) {
        int i = t + it * 256;
        int cl = i >> 4, q = i & 15;
#pragma unroll
        for (int j = 0; j < 4; ++j) {
            int p = q * 4 + j;
            s_t[cl][p] = (p < HW) ? ip[(size_t)cl * HW + p] : 0.f;
        }
    }
    __syncthreads();

    unsigned short* op = ipk + (size_t)b * HW * C + c0;
#pragma unroll
    for (int it = 0; it < 2; ++it) {
        int i = t + it * 256;
        int pl = i >> 3, gq = i & 7;
        if (pl < HW) {
            bf16x8 pk;
#pragma unroll
            for (int u = 0; u < 8; ++u)
                pk[u] = (short)f2bf(s_t[gq * 8 + u][pl]);
            *(bf16x8*)&op[(size_t)pl * C + gq * 8] = pk;
        }
    }
}

// ---------------------------------------------------------------------------
// L2 (fused): kconv (first nkc blocks) + search-input transpose (rest).
// ---------------------------------------------------------------------------
__global__ __launch_bounds__(256) void l2_fused(
    const float* __restrict__ sin_, unsigned short* __restrict__ ips,
    const unsigned short* __restrict__ ipk, const unsigned short* __restrict__ wkt,
    const float* __restrict__ bkg, const float* __restrict__ bkb,
    const float* __restrict__ bkm, const float* __restrict__ bkv,
    float* __restrict__ kbuf, int nkc)
{
    __shared__ __align__(16) char smem[16640];
    const int bid = blockIdx.x;
    const int t = threadIdx.x;

    if (bid < nkc) {
        constexpr int WIN = 7, HW = 49, WOUT = 5, NPOS = 25;
        constexpr int BPB = 2, PPB = 32, MF = 2, NF = 2;
        constexpr int APIX = 49, LDK = 40;
        constexpr int SLOTS_B = APIX * 4, SLOTS = BPB * SLOTS_B;
        constexpr int ITERS = 2;

        short* s_a = (short*)smem;

        const int lane = t & 63, wave = t >> 6;
        const int wm = wave >> 1, wn = wave & 1;
        const int lr = lane >> 4, lc = lane & 15;

        const int n0 = (bid & 3) * 64;
        const int b0 = (bid >> 2) * 2;

        int arow[MF];
#pragma unroll
        for (int m = 0; m < MF; ++m) {
            int pm = wm * 32 + m * 16 + lc;
            int bb = pm / PPB;
            int p = pm % PPB;
            p = p < NPOS ? p : NPOS - 1;
            int y = p / WOUT, x = p % WOUT;
            arow[m] = (bb * APIX + y * WIN + x) * LDK;
        }

        f32x4 acc[MF][NF];
#pragma unroll
        for (int m = 0; m < MF; ++m)
#pragma unroll
            for (int n = 0; n < NF; ++n) acc[m][n] = f32x4{0.f, 0.f, 0.f, 0.f};

        int sbb[ITERS], spx[ITERS], ssl[ITERS];
#pragma unroll
        for (int it = 0; it < ITERS; ++it) {
            int i = t + it * 256;
            int ii = i < SLOTS ? i : 0;
            int bb = ii / SLOTS_B;
            int r = ii - bb * SLOTS_B;
            sbb[it] = bb; spx[it] = r >> 2; ssl[it] = r & 3;
        }

        const unsigned short* wb = wkt + (size_t)(n0 + wn * 32 + lc) * C + lr * 8;

#define K_LOAD(c0_)                                                            \
        _Pragma("unroll")                                                      \
        for (int it = 0; it < ITERS; ++it) {                                   \
            const unsigned short* sp =                                         \
                ipk + ((size_t)(b0 + sbb[it]) * HW + spx[it]) * C + (c0_) + ssl[it] * 8; \
            stg[it] = *(const bf16x8*)sp;                                      \
        }
#define K_WRITE()                                                              \
        _Pragma("unroll")                                                      \
        for (int it = 0; it < ITERS; ++it)                                     \
            *(bf16x8*)&s_a[(sbb[it] * APIX + spx[it]) * LDK + ssl[it] * 8] = stg[it];

        {
            bf16x8 stg[ITERS];
            K_LOAD(0)
            K_WRITE()
        }

#pragma unroll 1
        for (int ch = 0; ch < 8; ++ch) {
            const int c0 = ch * 32;
            __syncthreads();

            bf16x8 stg[ITERS];
            if (ch < 7) { K_LOAD(c0 + 32) }

            bf16x8 bcur[NF], bnxt[NF];
#pragma unroll
            for (int n = 0; n < NF; ++n)
                bnxt[n] = *(const bf16x8*)&wb[(size_t)0 * (C * C) + n * (16 * C) + c0];

#pragma unroll
            for (int tap = 0; tap < 9; ++tap) {
                const int dy = tap / 3, dx = tap % 3;
#pragma unroll
                for (int n = 0; n < NF; ++n) bcur[n] = bnxt[n];
                if (tap < 8) {
#pragma unroll
                    for (int n = 0; n < NF; ++n)
                        bnxt[n] = *(const bf16x8*)&wb[(size_t)(tap + 1) * (C * C) + n * (16 * C) + c0];
                }
                bf16x8 af[MF];
#pragma unroll
                for (int m = 0; m < MF; ++m)
                    af[m] = *(const bf16x8*)&s_a[arow[m] + (dy * WIN + dx) * LDK + lr * 8];
#pragma unroll
                for (int m = 0; m < MF; ++m)
#pragma unroll
                    for (int n = 0; n < NF; ++n)
                        acc[m][n] = __builtin_amdgcn_mfma_f32_16x16x32_bf16(
                            af[m], bcur[n], acc[m][n], 0, 0, 0);
            }

            __syncthreads();
            if (ch < 7) { K_WRITE() }
        }
#undef K_LOAD
#undef K_WRITE

#pragma unroll
        for (int n = 0; n < NF; ++n) {
            const int co = n0 + wn * 32 + n * 16 + lc;
            const float sc = bkg[co] * rsqrtf(bkv[co] + BN_EPS);
            const float bias = bkb[co] - bkm[co] * sc;
#pragma unroll
            for (int m = 0; m < MF; ++m) {
                int pm = wm * 32 + m * 16 + lr * 4;
                int bb = pm / PPB;
                int p = pm % PPB;
                int b = b0 + bb;
                f32x4 v = acc[m][n];
                float rr[4] = {fmaxf(v.x + bias, 0.f), fmaxf(v.y + bias, 0.f),
                               fmaxf(v.z + bias, 0.f), fmaxf(v.w + bias, 0.f)};
                float* op = kbuf + ((size_t)b * C + co) * 28 + p;
#pragma unroll
                for (int i = 0; i < 4; ++i)
                    if (p + i < NPOS) op[i] = rr[i];
            }
        }
        return;
    }

    {
        constexpr int HW = 961;
        float (*s_t)[65] = (float(*)[65])smem;
        const int idx = bid - nkc;
        const int px0 = (idx & 15) * 64;
        const int c0 = ((idx >> 4) & 3) * 64;
        const int b = idx >> 6;
        const float* ip = sin_ + ((size_t)b * C + c0) * HW;

#pragma unroll
        for (int it = 0; it < 4; ++it) {
            int i = t + it * 256;
            int cl = i >> 4, q = i & 15;
#pragma unroll
            for (int j = 0; j < 4; ++j) {
                int p = px0 + q * 4 + j;
                s_t[cl][q * 4 + j] = (p < HW) ? ip[(size_t)cl * HW + p] : 0.f;
            }
        }
        __syncthreads();

        unsigned short* op = ips + (size_t)b * HW * C + (size_t)px0 * C + c0;
#pragma unroll
        for (int it = 0; it < 2; ++it) {
            int i = t + it * 256;
            int pl = i >> 3, gq = i & 7;
            if (px0 + pl < HW) {
                bf16x8 pk;
#pragma unroll
                for (int u = 0; u < 8; ++u)
                    pk[u] = (short)f2bf(s_t[gq * 8 + u][pl]);
                *(bf16x8*)&op[(size_t)pl * C + gq * 8] = pk;
            }
        }
    }
}

// ---------------------------------------------------------------------------
// SEARCH CONV v8 (r11 skeleton + T19 deterministic MFMA/DS_READ interleave):
// steps s=0..71; pairs with barrier every 2 steps; B 4-buf (LDK=36), A 2-buf.
// Emission pinned per pair: 11 DS_READ(s0) -> 27 MFMA(s0) interleaved with
// 11 DS_READ(s1) -> 1 MFMA -> 4 VMEM(B-stage, mid-pair) -> 28 MFMA(s1)
// -> 4 DS_WRITE. Keeps LDS port and matrix pipe concurrently busy.
// ---------------------------------------------------------------------------
__global__ __launch_bounds__(512, 2) void sconv_mfma(
    const unsigned short* __restrict__ in,   // [g][961][256] bf16
    const unsigned short* __restrict__ wt,   // [9][256][256] bf16
    const float* __restrict__ gamma, const float* __restrict__ beta,
    const float* __restrict__ mean, const float* __restrict__ var,
    unsigned short* __restrict__ outp)       // [g][256][844] bf16
{
    constexpr int WOUT = 29, NPOS = 841;
    constexpr int BM = 224, MF = 7, NF = 4;
    constexpr int LDK = 36;
    constexpr int ROWS = 11;
    constexpr int APIX = ROWS * 31;          // 341
    constexpr int ABUF = APIX * LDK;         // 12276 shorts
    constexpr int BBUF = 256 * LDK;          // 9216 shorts
    constexpr int AIT = 3;
    constexpr int BIT = 2;

    __shared__ __align__(16) short s_a[2 * ABUF];
    __shared__ __align__(16) short s_b[4 * BBUF];

    const int t = threadIdx.x;
    const int lane = t & 63, wave = t >> 6;
    const int wm = wave >> 2, wn = wave & 3;
    const int lr = lane >> 4, lc = lane & 15;

    const int p0 = blockIdx.x * BM;
    const int b  = blockIdx.y;
    const int y0 = p0 / WOUT;
    const int R  = min(ROWS, 31 - y0);
    const int npix = R * 31;

    const unsigned short* in_b = in + (size_t)b * (961 * 256);

    int arow[MF];
#pragma unroll
    for (int m = 0; m < MF; ++m) {
        int pm = wm * 112 + m * 16 + lc;
        int p = p0 + pm; p = p < NPOS ? p : NPOS - 1;
        int y = p / WOUT, x = p - y * WOUT;
        arow[m] = ((y - y0) * 31 + x) * LDK + lr * 8;
    }

    const unsigned short* aptr[AIT]; int aoff[AIT];
#pragma unroll
    for (int it = 0; it < AIT; ++it) {
        int i = t + it * 512;
        int px = i >> 2, sl = i & 3;
        px = px < npix ? px : 0;
        aptr[it] = in_b + (size_t)(y0 * 31 + px) * 256 + sl * 8;
        aoff[it] = px * LDK + sl * 8;
    }
    const unsigned short* bptr[BIT]; int boff[BIT];
#pragma unroll
    for (int it = 0; it < BIT; ++it) {
        int i = t + it * 512;
        int n = i >> 2, sl = i & 3;
        bptr[it] = wt + (size_t)n * 256 + sl * 8;
        boff[it] = n * LDK + sl * 8;
    }

    f32x4 acc[MF][NF];
#pragma unroll
    for (int m = 0; m < MF; ++m)
#pragma unroll
        for (int n = 0; n < NF; ++n) acc[m][n] = f32x4{0.f, 0.f, 0.f, 0.f};

    bf16x8 bstg0[BIT], bstg1[BIT], astg[AIT];

    // prologue: stage B steps 0,1 and A chunk 0
#pragma unroll
    for (int it = 0; it < BIT; ++it) bstg0[it] = *(const bf16x8*)(bptr[it]);
#pragma unroll
    for (int it = 0; it < BIT; ++it) bstg1[it] = *(const bf16x8*)(bptr[it] + 65536);
#pragma unroll
    for (int it = 0; it < AIT; ++it) astg[it] = *(const bf16x8*)(aptr[it]);
#pragma unroll
    for (int it = 0; it < BIT; ++it) *(bf16x8*)&s_b[boff[it]] = bstg0[it];
#pragma unroll
    for (int it = 0; it < BIT; ++it) *(bf16x8*)&s_b[BBUF + boff[it]] = bstg1[it];
#pragma unroll
    for (int it = 0; it < AIT; ++it) *(bf16x8*)&s_a[aoff[it]] = astg[it];
    __syncthreads();

#define READ_FRAGS(S, AF, BF)                                                  \
    {                                                                          \
        const int tap_ = (S) % 9;                                              \
        const int dt_ = (tap_ / 3) * 31 + (tap_ % 3);                          \
        const int ab_ = (((S) / 9) & 1) * ABUF;                                \
        const int bb_ = ((S) & 3) * BBUF;                                      \
        _Pragma("unroll")                                                      \
        for (int n = 0; n < NF; ++n)                                           \
            BF[n] = *(const bf16x8*)&s_b[bb_ + (wn * 64 + n * 16 + lc) * LDK + lr * 8]; \
        _Pragma("unroll")                                                      \
        for (int m = 0; m < MF; ++m)                                           \
            AF[m] = *(const bf16x8*)&s_a[ab_ + arow[m] + dt_ * LDK];           \
    }

#define MFMA_STEP(AF, BF)                                                      \
    _Pragma("unroll")                                                          \
    for (int m = 0; m < MF; ++m)                                               \
        _Pragma("unroll")                                                      \
        for (int n = 0; n < NF; ++n)                                           \
            acc[m][n] = __builtin_amdgcn_mfma_f32_16x16x32_bf16(               \
                AF[m], BF[n], acc[m][n], 0, 0, 0);

#pragma unroll 1
    for (int pr = 0; pr < 35; ++pr) {
        const int s0 = 2 * pr, s1 = s0 + 1;

        // A issue at chunk-start pair (wave-uniform branch, own region)
        {
            const int cb = (s0 % 9 == 0) ? s0 / 9 : ((s1 % 9 == 0) ? s1 / 9 : -1);
            if (cb >= 0 && cb < 7) {
                const int co_ = (cb + 1) * 32;
#pragma unroll
                for (int it = 0; it < AIT; ++it)
                    astg[it] = *(const bf16x8*)(aptr[it] + co_);
            }
        }

        // ---- straight-line region: reads + MFMAs + B-stage + B-writes ----
        bf16x8 af0[MF], bf0[NF], af1[MF], bf1[NF];
        READ_FRAGS(s0, af0, bf0)
        READ_FRAGS(s1, af1, bf1)

        MFMA_STEP(af0, bf0)

        // mid-pair B global issues for steps s0+2, s1+2 (shorter reg live range)
        {
            const int u0 = s0 + 2, u1 = s1 + 2;
            const int t0 = u0 % 9, c0_ = (u0 / 9) * 32;
            const int t1 = u1 % 9, c1_ = (u1 / 9) * 32;
#pragma unroll
            for (int it = 0; it < BIT; ++it)
                bstg0[it] = *(const bf16x8*)(bptr[it] + (size_t)t0 * 65536 + c0_);
#pragma unroll
            for (int it = 0; it < BIT; ++it)
                bstg1[it] = *(const bf16x8*)(bptr[it] + (size_t)t1 * 65536 + c1_);
        }

        MFMA_STEP(af1, bf1)

        // B pair-end writes
        {
            const int w0 = ((s0 + 2) & 3) * BBUF, w1 = ((s1 + 2) & 3) * BBUF;
#pragma unroll
            for (int it = 0; it < BIT; ++it)
                *(bf16x8*)&s_b[w0 + boff[it]] = bstg0[it];
#pragma unroll
            for (int it = 0; it < BIT; ++it)
                *(bf16x8*)&s_b[w1 + boff[it]] = bstg1[it];
        }

        // T19 pin: 11 rd | {3 MFMA,1 rd}x5 {2 MFMA,1 rd}x6 | 1 MFMA |
        //          4 vmem | 28 MFMA | 4 ds_write
        __builtin_amdgcn_sched_group_barrier(0x100, 11, 0);
#pragma unroll
        for (int q = 0; q < 5; ++q) {
            __builtin_amdgcn_sched_group_barrier(0x008, 3, 0);
            __builtin_amdgcn_sched_group_barrier(0x100, 1, 0);
        }
#pragma unroll
        for (int q = 0; q < 6; ++q) {
            __builtin_amdgcn_sched_group_barrier(0x008, 2, 0);
            __builtin_amdgcn_sched_group_barrier(0x100, 1, 0);
        }
        __builtin_amdgcn_sched_group_barrier(0x008, 1, 0);
        __builtin_amdgcn_sched_group_barrier(0x020, 4, 0);
        __builtin_amdgcn_sched_group_barrier(0x008, 28, 0);
        __builtin_amdgcn_sched_group_barrier(0x200, 4, 0);

        // A write at chunk-end pair (own region)
        {
            const int cw = (s0 % 9 == 7) ? s0 / 9 : ((s1 % 9 == 7) ? s1 / 9 : -1);
            if (cw >= 0 && cw < 7) {
                const int dst = ((cw & 1) ^ 1) * ABUF;
#pragma unroll
                for (int it = 0; it < AIT; ++it)
                    *(bf16x8*)&s_a[dst + aoff[it]] = astg[it];
            }
        }
        __syncthreads();
    }

    // final pair: s = 70, 71 (no prefetch, no writes)
    {
        bf16x8 af0[MF], bf0[NF], af1[MF], bf1[NF];
        READ_FRAGS(70, af0, bf0)
        READ_FRAGS(71, af1, bf1)
        MFMA_STEP(af0, bf0)
        MFMA_STEP(af1, bf1)
    }
#undef READ_FRAGS
#undef MFMA_STEP

    // epilogue: bias + relu -> bf16 planes (padded stride 844)
#pragma unroll
    for (int n = 0; n < NF; ++n) {
        const int co = wn * 64 + n * 16 + lc;
        const float sc = gamma[co] * rsqrtf(var[co] + BN_EPS);
        const float bias = beta[co] - mean[co] * sc;
#pragma unroll
        for (int m = 0; m < MF; ++m) {
            int pm = wm * 112 + m * 16 + lr * 4;
            int p = p0 + pm;
            f32x4 v = acc[m][n];
            float r0 = fmaxf(v.x + bias, 0.f);
            float r1 = fmaxf(v.y + bias, 0.f);
            float r2 = fmaxf(v.z + bias, 0.f);
            float r3 = fmaxf(v.w + bias, 0.f);
            unsigned short* op = outp + ((size_t)b * C + co) * 844 + p;
            if (p + 4 <= NPOS) {
                ushort4 pk;
                pk.x = f2bf(r0); pk.y = f2bf(r1); pk.z = f2bf(r2); pk.w = f2bf(r3);
                *(ushort4*)op = pk;
            } else {
                float rr[4] = {r0, r1, r2, r3};
#pragma unroll
                for (int i = 0; i < 4; ++i)
                    if (p + i < NPOS) op[i] = f2bf(rr[i]);
            }
        }
    }
}

// Depthwise 5x5 valid xcorr: s bf16 [g,C,844], k f32 [g,C,28] -> out f32 [g,C,625].
__global__ __launch_bounds__(256) void xcorr_dw(
    const unsigned short* __restrict__ s, const float* __restrict__ k,
    float* __restrict__ out)
{
    const int bc = blockIdx.x;
    const unsigned short* sp = s + (size_t)bc * 844;
    const float* kp = k + (size_t)bc * 28;
    float* op = out + (size_t)bc * 625;

    __shared__ float s_s[844];
    __shared__ float s_k[25];
    const int t = threadIdx.x;
    if (t < 211) {
        ushort4 v = *(const ushort4*)(sp + 4 * t);
        s_s[4 * t + 0] = bf2f(v.x);
        s_s[4 * t + 1] = bf2f(v.y);
        s_s[4 * t + 2] = bf2f(v.z);
        s_s[4 * t + 3] = bf2f(v.w);
    }
    if (t < 25) s_k[t] = kp[t];
    __syncthreads();

    float kk[25];
#pragma unroll
    for (int i = 0; i < 25; ++i) kk[i] = s_k[i];

#pragma unroll
    for (int j = 0; j < 3; ++j) {
        int pos = t + j * 256;
        if (pos < 625) {
            int y = pos / 25, x = pos - y * 25;
            float a = 0.f;
#pragma unroll
            for (int dy = 0; dy < 5; ++dy)
#pragma unroll
                for (int dx = 0; dx < 5; ++dx)
                    a += s_s[(y + dy) * 29 + x + dx] * kk[dy * 5 + dx];
            op[pos] = a;
        }
    }
}

extern "C" void kernel_launch(void* const* d_in, const int* in_sizes, int n_in,
                              void* d_out, int out_size, void* d_ws, size_t ws_size,
                              hipStream_t stream) {
    const float* kin = (const float*)d_in[0];   // [128,256,7,7]
    const float* sin_ = (const float*)d_in[1];  // [128,256,31,31]
    const float* wk = (const float*)d_in[2];
    const float* bkg = (const float*)d_in[3];
    const float* bkb = (const float*)d_in[4];
    const float* bkm = (const float*)d_in[5];
    const float* bkv = (const float*)d_in[6];
    const float* ws_ = (const float*)d_in[7];
    const float* bsg = (const float*)d_in[8];
    const float* bsb = (const float*)d_in[9];
    const float* bsm = (const float*)d_in[10];
    const float* bsv = (const float*)d_in[11];
    float* out = (float*)d_out;

    char* base = (char*)d_ws;
    unsigned short* wkt = (unsigned short*)base;               // 1,179,648 B
    unsigned short* wst = wkt + (size_t)9 * C * C;
    char* gbase = base + 2359296;

    const size_t perb_is = (size_t)961 * C * 2;  // 492032
    const size_t perb_ik = (size_t)49 * C * 2;   // 25088
    const size_t perb_sb = (size_t)844 * C * 2;  // 432128
    const size_t perb_kb = (size_t)28 * C * 4;   // 28672
    const size_t perb = perb_is + perb_ik + perb_sb + perb_kb; // 977920

    int G = (int)((ws_size - 2359296) / perb);
    if (G > 128) G = 128;
    G &= ~1;
    if (G < 2) G = 2;

    unsigned short* ips  = (unsigned short*)gbase;
    unsigned short* ipk  = (unsigned short*)(gbase + (size_t)G * perb_is);
    unsigned short* sbuf = (unsigned short*)(gbase + (size_t)G * (perb_is + perb_ik));
    float*          kbuf = (float*)(gbase + (size_t)G * (perb_is + perb_ik + perb_sb));

    for (int g0 = 0; g0 < 128; g0 += G) {
        const int g = (128 - g0) < G ? (128 - g0) : G;
        const int nw = (g0 == 0) ? 512 : 0;

        prep_fused<<<nw + 4 * g, 256, 0, stream>>>(
            wk, bkg, bkv, wkt, ws_, bsg, bsv, wst,
            kin + (size_t)g0 * C * 49, ipk, nw);

        const int nkc = 2 * g;
        l2_fused<<<nkc + 64 * g, 256, 0, stream>>>(
            sin_ + (size_t)g0 * C * 961, ips, ipk, wkt,
            bkg, bkb, bkm, bkv, kbuf, nkc);

        sconv_mfma<<<dim3(4, g), 512, 0, stream>>>(
            ips, wst, bsg, bsb, bsm, bsv, sbuf);

        xcorr_dw<<<(unsigned)g * C, 256, 0, stream>>>(
            sbuf, kbuf, out + (size_t)g0 * C * 625);
    }
}

// Round 13
// 262.151 us; speedup vs baseline: 1.3316x; 1.1000x over previous
//
#include <hip/hip_runtime.h>
#include <hip/hip_bf16.h>

#define BN_EPS 1e-5f
constexpr int C = 256;

typedef __attribute__((ext_vector_type(8))) short bf16x8;
typedef __attribute__((ext_vector_type(4))) float f32x4;

static __device__ __forceinline__ unsigned short f2bf(float f) {
    __hip_bfloat16 h = __float2bfloat16(f);
    return *reinterpret_cast<unsigned short*>(&h);
}
static __device__ __forceinline__ float bf2f(unsigned short u) {
    unsigned int v = ((unsigned int)u) << 16;
    return __uint_as_float(v);
}

// ---------------------------------------------------------------------------
// L1 PREP (fused): wprep(kernel) + wprep(search) + kernel-input transpose.
// ---------------------------------------------------------------------------
__global__ __launch_bounds__(256) void prep_fused(
    const float* __restrict__ wk, const float* __restrict__ bkg, const float* __restrict__ bkv,
    unsigned short* __restrict__ wkt,
    const float* __restrict__ ws, const float* __restrict__ bsg, const float* __restrict__ bsv,
    unsigned short* __restrict__ wst,
    const float* __restrict__ kin, unsigned short* __restrict__ ipk,
    int nw)
{
    __shared__ float s_t[64][65];
    const int bid = blockIdx.x;
    const int t = threadIdx.x;

    if (bid < nw) {
        const bool isk = bid < (nw >> 1);
        const int n = isk ? bid : bid - (nw >> 1);
        const float* w = isk ? wk : ws;
        const float* g = isk ? bkg : bsg;
        const float* v = isk ? bkv : bsv;
        unsigned short* wt = isk ? wkt : wst;
        const float scale = g[n] * rsqrtf(v[n] + BN_EPS);
        const float* wp = w + ((size_t)n * C + t) * 9;
#pragma unroll
        for (int k = 0; k < 9; ++k)
            wt[((size_t)k * C + n) * C + t] = f2bf(wp[k] * scale);
        return;
    }

    const int idx = bid - nw;
    const int b = idx >> 2, c0 = (idx & 3) * 64;
    constexpr int HW = 49;
    const float* ip = kin + ((size_t)b * C + c0) * HW;

#pragma unroll
    for (int it = 0; it < 4; ++it) {
        int i = t + it * 256;
        int cl = i >> 4, q = i & 15;
#pragma unroll
        for (int j = 0; j < 4; ++j) {
            int p = q * 4 + j;
            s_t[cl][p] = (p < HW) ? ip[(size_t)cl * HW + p] : 0.f;
        }
    }
    __syncthreads();

    unsigned short* op = ipk + (size_t)b * HW * C + c0;
#pragma unroll
    for (int it = 0; it < 2; ++it) {
        int i = t + it * 256;
        int pl = i >> 3, gq = i & 7;
        if (pl < HW) {
            bf16x8 pk;
#pragma unroll
            for (int u = 0; u < 8; ++u)
                pk[u] = (short)f2bf(s_t[gq * 8 + u][pl]);
            *(bf16x8*)&op[(size_t)pl * C + gq * 8] = pk;
        }
    }
}

// ---------------------------------------------------------------------------
// L2 (fused): kconv (first nkc blocks) + search-input transpose (rest).
// ---------------------------------------------------------------------------
__global__ __launch_bounds__(256) void l2_fused(
    const float* __restrict__ sin_, unsigned short* __restrict__ ips,
    const unsigned short* __restrict__ ipk, const unsigned short* __restrict__ wkt,
    const float* __restrict__ bkg, const float* __restrict__ bkb,
    const float* __restrict__ bkm, const float* __restrict__ bkv,
    float* __restrict__ kbuf, int nkc)
{
    __shared__ __align__(16) char smem[16640];
    const int bid = blockIdx.x;
    const int t = threadIdx.x;

    if (bid < nkc) {
        constexpr int WIN = 7, HW = 49, WOUT = 5, NPOS = 25;
        constexpr int BPB = 2, PPB = 32, MF = 2, NF = 2;
        constexpr int APIX = 49, LDK = 40;
        constexpr int SLOTS_B = APIX * 4, SLOTS = BPB * SLOTS_B;
        constexpr int ITERS = 2;

        short* s_a = (short*)smem;

        const int lane = t & 63, wave = t >> 6;
        const int wm = wave >> 1, wn = wave & 1;
        const int lr = lane >> 4, lc = lane & 15;

        const int n0 = (bid & 3) * 64;
        const int b0 = (bid >> 2) * 2;

        int arow[MF];
#pragma unroll
        for (int m = 0; m < MF; ++m) {
            int pm = wm * 32 + m * 16 + lc;
            int bb = pm / PPB;
            int p = pm % PPB;
            p = p < NPOS ? p : NPOS - 1;
            int y = p / WOUT, x = p % WOUT;
            arow[m] = (bb * APIX + y * WIN + x) * LDK;
        }

        f32x4 acc[MF][NF];
#pragma unroll
        for (int m = 0; m < MF; ++m)
#pragma unroll
            for (int n = 0; n < NF; ++n) acc[m][n] = f32x4{0.f, 0.f, 0.f, 0.f};

        int sbb[ITERS], spx[ITERS], ssl[ITERS];
#pragma unroll
        for (int it = 0; it < ITERS; ++it) {
            int i = t + it * 256;
            int ii = i < SLOTS ? i : 0;
            int bb = ii / SLOTS_B;
            int r = ii - bb * SLOTS_B;
            sbb[it] = bb; spx[it] = r >> 2; ssl[it] = r & 3;
        }

        const unsigned short* wb = wkt + (size_t)(n0 + wn * 32 + lc) * C + lr * 8;

#define K_LOAD(c0_)                                                            \
        _Pragma("unroll")                                                      \
        for (int it = 0; it < ITERS; ++it) {                                   \
            const unsigned short* sp =                                         \
                ipk + ((size_t)(b0 + sbb[it]) * HW + spx[it]) * C + (c0_) + ssl[it] * 8; \
            stg[it] = *(const bf16x8*)sp;                                      \
        }
#define K_WRITE()                                                              \
        _Pragma("unroll")                                                      \
        for (int it = 0; it < ITERS; ++it)                                     \
            *(bf16x8*)&s_a[(sbb[it] * APIX + spx[it]) * LDK + ssl[it] * 8] = stg[it];

        {
            bf16x8 stg[ITERS];
            K_LOAD(0)
            K_WRITE()
        }

#pragma unroll 1
        for (int ch = 0; ch < 8; ++ch) {
            const int c0 = ch * 32;
            __syncthreads();

            bf16x8 stg[ITERS];
            if (ch < 7) { K_LOAD(c0 + 32) }

            bf16x8 bcur[NF], bnxt[NF];
#pragma unroll
            for (int n = 0; n < NF; ++n)
                bnxt[n] = *(const bf16x8*)&wb[(size_t)0 * (C * C) + n * (16 * C) + c0];

#pragma unroll
            for (int tap = 0; tap < 9; ++tap) {
                const int dy = tap / 3, dx = tap % 3;
#pragma unroll
                for (int n = 0; n < NF; ++n) bcur[n] = bnxt[n];
                if (tap < 8) {
#pragma unroll
                    for (int n = 0; n < NF; ++n)
                        bnxt[n] = *(const bf16x8*)&wb[(size_t)(tap + 1) * (C * C) + n * (16 * C) + c0];
                }
                bf16x8 af[MF];
#pragma unroll
                for (int m = 0; m < MF; ++m)
                    af[m] = *(const bf16x8*)&s_a[arow[m] + (dy * WIN + dx) * LDK + lr * 8];
#pragma unroll
                for (int m = 0; m < MF; ++m)
#pragma unroll
                    for (int n = 0; n < NF; ++n)
                        acc[m][n] = __builtin_amdgcn_mfma_f32_16x16x32_bf16(
                            af[m], bcur[n], acc[m][n], 0, 0, 0);
            }

            __syncthreads();
            if (ch < 7) { K_WRITE() }
        }
#undef K_LOAD
#undef K_WRITE

#pragma unroll
        for (int n = 0; n < NF; ++n) {
            const int co = n0 + wn * 32 + n * 16 + lc;
            const float sc = bkg[co] * rsqrtf(bkv[co] + BN_EPS);
            const float bias = bkb[co] - bkm[co] * sc;
#pragma unroll
            for (int m = 0; m < MF; ++m) {
                int pm = wm * 32 + m * 16 + lr * 4;
                int bb = pm / PPB;
                int p = pm % PPB;
                int b = b0 + bb;
                f32x4 v = acc[m][n];
                float rr[4] = {fmaxf(v.x + bias, 0.f), fmaxf(v.y + bias, 0.f),
                               fmaxf(v.z + bias, 0.f), fmaxf(v.w + bias, 0.f)};
                float* op = kbuf + ((size_t)b * C + co) * 28 + p;
#pragma unroll
                for (int i = 0; i < 4; ++i)
                    if (p + i < NPOS) op[i] = rr[i];
            }
        }
        return;
    }

    {
        constexpr int HW = 961;
        float (*s_t)[65] = (float(*)[65])smem;
        const int idx = bid - nkc;
        const int px0 = (idx & 15) * 64;
        const int c0 = ((idx >> 4) & 3) * 64;
        const int b = idx >> 6;
        const float* ip = sin_ + ((size_t)b * C + c0) * HW;

#pragma unroll
        for (int it = 0; it < 4; ++it) {
            int i = t + it * 256;
            int cl = i >> 4, q = i & 15;
#pragma unroll
            for (int j = 0; j < 4; ++j) {
                int p = px0 + q * 4 + j;
                s_t[cl][q * 4 + j] = (p < HW) ? ip[(size_t)cl * HW + p] : 0.f;
            }
        }
        __syncthreads();

        unsigned short* op = ips + (size_t)b * HW * C + (size_t)px0 * C + c0;
#pragma unroll
        for (int it = 0; it < 2; ++it) {
            int i = t + it * 256;
            int pl = i >> 3, gq = i & 7;
            if (px0 + pl < HW) {
                bf16x8 pk;
#pragma unroll
                for (int u = 0; u < 8; ++u)
                    pk[u] = (short)f2bf(s_t[gq * 8 + u][pl]);
                *(bf16x8*)&op[(size_t)pl * C + gq * 8] = pk;
            }
        }
    }
}

// ---------------------------------------------------------------------------
// SEARCH CONV v8 (unchanged from r12): paired-step barriers, 4x B-buf
// (LDK=36), A 2-buf, T19 interleave pins.
// ---------------------------------------------------------------------------
__global__ __launch_bounds__(512, 2) void sconv_mfma(
    const unsigned short* __restrict__ in,   // [g][961][256] bf16
    const unsigned short* __restrict__ wt,   // [9][256][256] bf16
    const float* __restrict__ gamma, const float* __restrict__ beta,
    const float* __restrict__ mean, const float* __restrict__ var,
    unsigned short* __restrict__ outp)       // [g][256][844] bf16
{
    constexpr int WOUT = 29, NPOS = 841;
    constexpr int BM = 224, MF = 7, NF = 4;
    constexpr int LDK = 36;
    constexpr int ROWS = 11;
    constexpr int APIX = ROWS * 31;          // 341
    constexpr int ABUF = APIX * LDK;         // 12276 shorts
    constexpr int BBUF = 256 * LDK;          // 9216 shorts
    constexpr int AIT = 3;
    constexpr int BIT = 2;

    __shared__ __align__(16) short s_a[2 * ABUF];
    __shared__ __align__(16) short s_b[4 * BBUF];

    const int t = threadIdx.x;
    const int lane = t & 63, wave = t >> 6;
    const int wm = wave >> 2, wn = wave & 3;
    const int lr = lane >> 4, lc = lane & 15;

    const int p0 = blockIdx.x * BM;
    const int b  = blockIdx.y;
    const int y0 = p0 / WOUT;
    const int R  = min(ROWS, 31 - y0);
    const int npix = R * 31;

    const unsigned short* in_b = in + (size_t)b * (961 * 256);

    int arow[MF];
#pragma unroll
    for (int m = 0; m < MF; ++m) {
        int pm = wm * 112 + m * 16 + lc;
        int p = p0 + pm; p = p < NPOS ? p : NPOS - 1;
        int y = p / WOUT, x = p - y * WOUT;
        arow[m] = ((y - y0) * 31 + x) * LDK + lr * 8;
    }

    const unsigned short* aptr[AIT]; int aoff[AIT];
#pragma unroll
    for (int it = 0; it < AIT; ++it) {
        int i = t + it * 512;
        int px = i >> 2, sl = i & 3;
        px = px < npix ? px : 0;
        aptr[it] = in_b + (size_t)(y0 * 31 + px) * 256 + sl * 8;
        aoff[it] = px * LDK + sl * 8;
    }
    const unsigned short* bptr[BIT]; int boff[BIT];
#pragma unroll
    for (int it = 0; it < BIT; ++it) {
        int i = t + it * 512;
        int n = i >> 2, sl = i & 3;
        bptr[it] = wt + (size_t)n * 256 + sl * 8;
        boff[it] = n * LDK + sl * 8;
    }

    f32x4 acc[MF][NF];
#pragma unroll
    for (int m = 0; m < MF; ++m)
#pragma unroll
        for (int n = 0; n < NF; ++n) acc[m][n] = f32x4{0.f, 0.f, 0.f, 0.f};

    bf16x8 bstg0[BIT], bstg1[BIT], astg[AIT];

    // prologue: stage B steps 0,1 and A chunk 0
#pragma unroll
    for (int it = 0; it < BIT; ++it) bstg0[it] = *(const bf16x8*)(bptr[it]);
#pragma unroll
    for (int it = 0; it < BIT; ++it) bstg1[it] = *(const bf16x8*)(bptr[it] + 65536);
#pragma unroll
    for (int it = 0; it < AIT; ++it) astg[it] = *(const bf16x8*)(aptr[it]);
#pragma unroll
    for (int it = 0; it < BIT; ++it) *(bf16x8*)&s_b[boff[it]] = bstg0[it];
#pragma unroll
    for (int it = 0; it < BIT; ++it) *(bf16x8*)&s_b[BBUF + boff[it]] = bstg1[it];
#pragma unroll
    for (int it = 0; it < AIT; ++it) *(bf16x8*)&s_a[aoff[it]] = astg[it];
    __syncthreads();

#define READ_FRAGS(S, AF, BF)                                                  \
    {                                                                          \
        const int tap_ = (S) % 9;                                              \
        const int dt_ = (tap_ / 3) * 31 + (tap_ % 3);                          \
        const int ab_ = (((S) / 9) & 1) * ABUF;                                \
        const int bb_ = ((S) & 3) * BBUF;                                      \
        _Pragma("unroll")                                                      \
        for (int n = 0; n < NF; ++n)                                           \
            BF[n] = *(const bf16x8*)&s_b[bb_ + (wn * 64 + n * 16 + lc) * LDK + lr * 8]; \
        _Pragma("unroll")                                                      \
        for (int m = 0; m < MF; ++m)                                           \
            AF[m] = *(const bf16x8*)&s_a[ab_ + arow[m] + dt_ * LDK];           \
    }

#define MFMA_STEP(AF, BF)                                                      \
    _Pragma("unroll")                                                          \
    for (int m = 0; m < MF; ++m)                                               \
        _Pragma("unroll")                                                      \
        for (int n = 0; n < NF; ++n)                                           \
            acc[m][n] = __builtin_amdgcn_mfma_f32_16x16x32_bf16(               \
                AF[m], BF[n], acc[m][n], 0, 0, 0);

#pragma unroll 1
    for (int pr = 0; pr < 35; ++pr) {
        const int s0 = 2 * pr, s1 = s0 + 1;

        {
            const int cb = (s0 % 9 == 0) ? s0 / 9 : ((s1 % 9 == 0) ? s1 / 9 : -1);
            if (cb >= 0 && cb < 7) {
                const int co_ = (cb + 1) * 32;
#pragma unroll
                for (int it = 0; it < AIT; ++it)
                    astg[it] = *(const bf16x8*)(aptr[it] + co_);
            }
        }

        bf16x8 af0[MF], bf0[NF], af1[MF], bf1[NF];
        READ_FRAGS(s0, af0, bf0)
        READ_FRAGS(s1, af1, bf1)

        MFMA_STEP(af0, bf0)

        {
            const int u0 = s0 + 2, u1 = s1 + 2;
            const int t0 = u0 % 9, c0_ = (u0 / 9) * 32;
            const int t1 = u1 % 9, c1_ = (u1 / 9) * 32;
#pragma unroll
            for (int it = 0; it < BIT; ++it)
                bstg0[it] = *(const bf16x8*)(bptr[it] + (size_t)t0 * 65536 + c0_);
#pragma unroll
            for (int it = 0; it < BIT; ++it)
                bstg1[it] = *(const bf16x8*)(bptr[it] + (size_t)t1 * 65536 + c1_);
        }

        MFMA_STEP(af1, bf1)

        {
            const int w0 = ((s0 + 2) & 3) * BBUF, w1 = ((s1 + 2) & 3) * BBUF;
#pragma unroll
            for (int it = 0; it < BIT; ++it)
                *(bf16x8*)&s_b[w0 + boff[it]] = bstg0[it];
#pragma unroll
            for (int it = 0; it < BIT; ++it)
                *(bf16x8*)&s_b[w1 + boff[it]] = bstg1[it];
        }

        __builtin_amdgcn_sched_group_barrier(0x100, 11, 0);
#pragma unroll
        for (int q = 0; q < 5; ++q) {
            __builtin_amdgcn_sched_group_barrier(0x008, 3, 0);
            __builtin_amdgcn_sched_group_barrier(0x100, 1, 0);
        }
#pragma unroll
        for (int q = 0; q < 6; ++q) {
            __builtin_amdgcn_sched_group_barrier(0x008, 2, 0);
            __builtin_amdgcn_sched_group_barrier(0x100, 1, 0);
        }
        __builtin_amdgcn_sched_group_barrier(0x008, 1, 0);
        __builtin_amdgcn_sched_group_barrier(0x020, 4, 0);
        __builtin_amdgcn_sched_group_barrier(0x008, 28, 0);
        __builtin_amdgcn_sched_group_barrier(0x200, 4, 0);

        {
            const int cw = (s0 % 9 == 7) ? s0 / 9 : ((s1 % 9 == 7) ? s1 / 9 : -1);
            if (cw >= 0 && cw < 7) {
                const int dst = ((cw & 1) ^ 1) * ABUF;
#pragma unroll
                for (int it = 0; it < AIT; ++it)
                    *(bf16x8*)&s_a[dst + aoff[it]] = astg[it];
            }
        }
        __syncthreads();
    }

    {
        bf16x8 af0[MF], bf0[NF], af1[MF], bf1[NF];
        READ_FRAGS(70, af0, bf0)
        READ_FRAGS(71, af1, bf1)
        MFMA_STEP(af0, bf0)
        MFMA_STEP(af1, bf1)
    }
#undef READ_FRAGS
#undef MFMA_STEP

    // epilogue: bias + relu -> bf16 planes (padded stride 844)
#pragma unroll
    for (int n = 0; n < NF; ++n) {
        const int co = wn * 64 + n * 16 + lc;
        const float sc = gamma[co] * rsqrtf(var[co] + BN_EPS);
        const float bias = beta[co] - mean[co] * sc;
#pragma unroll
        for (int m = 0; m < MF; ++m) {
            int pm = wm * 112 + m * 16 + lr * 4;
            int p = p0 + pm;
            f32x4 v = acc[m][n];
            float r0 = fmaxf(v.x + bias, 0.f);
            float r1 = fmaxf(v.y + bias, 0.f);
            float r2 = fmaxf(v.z + bias, 0.f);
            float r3 = fmaxf(v.w + bias, 0.f);
            unsigned short* op = outp + ((size_t)b * C + co) * 844 + p;
            if (p + 4 <= NPOS) {
                ushort4 pk;
                pk.x = f2bf(r0); pk.y = f2bf(r1); pk.z = f2bf(r2); pk.w = f2bf(r3);
                *(ushort4*)op = pk;
            } else {
                float rr[4] = {r0, r1, r2, r3};
#pragma unroll
                for (int i = 0; i < 4; ++i)
                    if (p + i < NPOS) op[i] = f2bf(rr[i]);
            }
        }
    }
}

// ---------------------------------------------------------------------------
// Depthwise 5x5 valid xcorr v2: 2 channels/block, 5 outputs/thread with a
// 5x9 register window (45 LDS reads per 5 outputs vs 125 before).
// s bf16 [g,C,844], k f32 [g,C,28] -> out f32 [g,C,625].
// ---------------------------------------------------------------------------
__global__ __launch_bounds__(256) void xcorr_dw(
    const unsigned short* __restrict__ s, const float* __restrict__ k,
    float* __restrict__ out)
{
    const int bc0 = blockIdx.x * 2;
    const int t = threadIdx.x;

    __shared__ float s_s[2][844];
    __shared__ float s_k[2][25];

    // stage both planes (844 shorts = 211 ushort4 each)
#pragma unroll
    for (int it = 0; it < 2; ++it) {
        int i = t + it * 256;
        if (i < 422) {
            int pl = i < 211 ? 0 : 1;
            int q = i - pl * 211;
            ushort4 v = *(const ushort4*)(s + (size_t)(bc0 + pl) * 844 + 4 * q);
            s_s[pl][4 * q + 0] = bf2f(v.x);
            s_s[pl][4 * q + 1] = bf2f(v.y);
            s_s[pl][4 * q + 2] = bf2f(v.z);
            s_s[pl][4 * q + 3] = bf2f(v.w);
        }
    }
    if (t < 50) s_k[t / 25][t % 25] = k[(size_t)(bc0 + t / 25) * 28 + t % 25];
    __syncthreads();

    if (t >= 250) return;
    const int ch = t / 125;
    const int r = t - ch * 125;
    const int y = r / 5;
    const int xb = (r - y * 5) * 5;

    float kk[25];
#pragma unroll
    for (int i = 0; i < 25; ++i) kk[i] = s_k[ch][i];

    // 5x9 register window
    float w[5][9];
#pragma unroll
    for (int dy = 0; dy < 5; ++dy)
#pragma unroll
        for (int dx = 0; dx < 9; ++dx)
            w[dy][dx] = s_s[ch][(y + dy) * 29 + xb + dx];

    float o[5] = {0.f, 0.f, 0.f, 0.f, 0.f};
#pragma unroll
    for (int dy = 0; dy < 5; ++dy)
#pragma unroll
        for (int dx = 0; dx < 5; ++dx) {
            const float kv = kk[dy * 5 + dx];
#pragma unroll
            for (int oo = 0; oo < 5; ++oo)
                o[oo] += w[dy][oo + dx] * kv;
        }

    float* op = out + (size_t)(bc0 + ch) * 625 + y * 25 + xb;
#pragma unroll
    for (int oo = 0; oo < 5; ++oo) op[oo] = o[oo];
}

extern "C" void kernel_launch(void* const* d_in, const int* in_sizes, int n_in,
                              void* d_out, int out_size, void* d_ws, size_t ws_size,
                              hipStream_t stream) {
    const float* kin = (const float*)d_in[0];   // [128,256,7,7]
    const float* sin_ = (const float*)d_in[1];  // [128,256,31,31]
    const float* wk = (const float*)d_in[2];
    const float* bkg = (const float*)d_in[3];
    const float* bkb = (const float*)d_in[4];
    const float* bkm = (const float*)d_in[5];
    const float* bkv = (const float*)d_in[6];
    const float* ws_ = (const float*)d_in[7];
    const float* bsg = (const float*)d_in[8];
    const float* bsb = (const float*)d_in[9];
    const float* bsm = (const float*)d_in[10];
    const float* bsv = (const float*)d_in[11];
    float* out = (float*)d_out;

    char* base = (char*)d_ws;
    unsigned short* wkt = (unsigned short*)base;               // 1,179,648 B
    unsigned short* wst = wkt + (size_t)9 * C * C;
    char* gbase = base + 2359296;

    const size_t perb_is = (size_t)961 * C * 2;  // 492032
    const size_t perb_ik = (size_t)49 * C * 2;   // 25088
    const size_t perb_sb = (size_t)844 * C * 2;  // 432128
    const size_t perb_kb = (size_t)28 * C * 4;   // 28672
    const size_t perb = perb_is + perb_ik + perb_sb + perb_kb; // 977920

    int G = (int)((ws_size - 2359296) / perb);
    if (G > 128) G = 128;
    G &= ~1;
    if (G < 2) G = 2;

    unsigned short* ips  = (unsigned short*)gbase;
    unsigned short* ipk  = (unsigned short*)(gbase + (size_t)G * perb_is);
    unsigned short* sbuf = (unsigned short*)(gbase + (size_t)G * (perb_is + perb_ik));
    float*          kbuf = (float*)(gbase + (size_t)G * (perb_is + perb_ik + perb_sb));

    for (int g0 = 0; g0 < 128; g0 += G) {
        const int g = (128 - g0) < G ? (128 - g0) : G;
        const int nw = (g0 == 0) ? 512 : 0;

        prep_fused<<<nw + 4 * g, 256, 0, stream>>>(
            wk, bkg, bkv, wkt, ws_, bsg, bsv, wst,
            kin + (size_t)g0 * C * 49, ipk, nw);

        const int nkc = 2 * g;
        l2_fused<<<nkc + 64 * g, 256, 0, stream>>>(
            sin_ + (size_t)g0 * C * 961, ips, ipk, wkt,
            bkg, bkb, bkm, bkv, kbuf, nkc);

        sconv_mfma<<<dim3(4, g), 512, 0, stream>>>(
            ips, wst, bsg, bsb, bsm, bsv, sbuf);

        xcorr_dw<<<(unsigned)g * (C / 2), 256, 0, stream>>>(
            sbuf, kbuf, out + (size_t)g0 * C * 625);
    }
}

// Round 14
// 224.182 us; speedup vs baseline: 1.5571x; 1.1694x over previous
//
#include <hip/hip_runtime.h>
#include <hip/hip_bf16.h>

#define BN_EPS 1e-5f
constexpr int C = 256;

typedef __attribute__((ext_vector_type(8))) short bf16x8;
typedef __attribute__((ext_vector_type(4))) float f32x4;

static __device__ __forceinline__ unsigned short f2bf(float f) {
    __hip_bfloat16 h = __float2bfloat16(f);
    return *reinterpret_cast<unsigned short*>(&h);
}
static __device__ __forceinline__ float bf2f(unsigned short u) {
    unsigned int v = ((unsigned int)u) << 16;
    return __uint_as_float(v);
}
static __device__ __forceinline__ unsigned int pack_bf2(float a, float b) {
    return (unsigned int)f2bf(a) | ((unsigned int)f2bf(b) << 16);
}

// ---------------------------------------------------------------------------
// WPREP: fold BN scale into weights, transpose [N][C][9] f32 -> [9][N][C] bf16.
// 512 blocks: [0,256) kernel-weights, [256,512) search-weights.
// ---------------------------------------------------------------------------
__global__ __launch_bounds__(256) void wprep_both(
    const float* __restrict__ wk, const float* __restrict__ bkg, const float* __restrict__ bkv,
    unsigned short* __restrict__ wkt,
    const float* __restrict__ ws, const float* __restrict__ bsg, const float* __restrict__ bsv,
    unsigned short* __restrict__ wst)
{
    const int bid = blockIdx.x, t = threadIdx.x;
    const bool isk = bid < 256;
    const int n = isk ? bid : bid - 256;
    const float* w = isk ? wk : ws;
    const float* g = isk ? bkg : bsg;
    const float* v = isk ? bkv : bsv;
    unsigned short* wt = isk ? wkt : wst;
    const float scale = g[n] * rsqrtf(v[n] + BN_EPS);
    const float* wp = w + ((size_t)n * C + t) * 9;
#pragma unroll
    for (int k = 0; k < 9; ++k)
        wt[((size_t)k * C + n) * C + t] = f2bf(wp[k] * scale);
}

// ---------------------------------------------------------------------------
// MEGA: blocks [0,512) = search conv (transpose-free A staging from fp32
// NCHW), blocks [512,640) = kernel conv (also transpose-free).
// 512 thr = 8 waves. Uniform LDS union (sconv's 123 KB dominates).
// ---------------------------------------------------------------------------
__global__ __launch_bounds__(512, 2) void mega_conv(
    const float* __restrict__ sin_,          // [128][256][961] fp32
    const float* __restrict__ kin,           // [128][256][49]  fp32
    const unsigned short* __restrict__ wst,  // [9][256][256] bf16
    const unsigned short* __restrict__ wkt,  // [9][256][256] bf16
    const float* __restrict__ bsg, const float* __restrict__ bsb,
    const float* __restrict__ bsm, const float* __restrict__ bsv,
    const float* __restrict__ bkg, const float* __restrict__ bkb,
    const float* __restrict__ bkm, const float* __restrict__ bkv,
    unsigned short* __restrict__ sbuf,       // [128][256][844] bf16
    float* __restrict__ kbuf)                // [128][256][28]  f32
{
    constexpr int WOUT = 29, NPOS = 841;
    constexpr int BM = 224, MF = 7, NF = 4;
    constexpr int LDK = 36;
    constexpr int ROWS = 11;
    constexpr int APIX = ROWS * 31;          // 341
    constexpr int ABUF = APIX * LDK;         // 12276 shorts
    constexpr int BBUF = 256 * LDK;          // 9216 shorts
    constexpr int BIT = 2;

    __shared__ __align__(16) short s_a[2 * ABUF];   // 49,104 B (kconv reuses)
    __shared__ __align__(16) short s_b[4 * BBUF];   // 73,728 B

    const int bid = blockIdx.x;
    const int t = threadIdx.x;
    const int lane = t & 63, wave = t >> 6;
    const int lr = lane >> 4, lc = lane & 15;

    if (bid >= 512) {
        // ================= KERNEL CONV role =================
        // 7x7 -> 5x5. BM=64 (2 batches x 25+pad), BN=128. 8 waves 2wm x 4wn,
        // wave tile 32x32 (MF=2, NF=2). A staged from fp32 NCHW directly.
        constexpr int KW = 7, KHW = 49, KWOUT = 5, KNPOS = 25;
        constexpr int KMF = 2, KNF = 2;
        const int kb = bid - 512;            // 0..127
        const int n0 = (kb & 1) * 128;
        const int b0 = (kb >> 1) * 2;
        const int wm = wave >> 2, wn = wave & 3;

        short* ka = s_a;                      // [2*49][36] shorts

        int arow[KMF];
#pragma unroll
        for (int m = 0; m < KMF; ++m) {
            int p = m * 16 + lc;
            p = p < KNPOS ? p : KNPOS - 1;
            int y = p / KWOUT, x = p - y * KWOUT;
            arow[m] = ((wm * KHW) + y * KW + x) * LDK + lr * 8;
        }

        f32x4 acc[KMF][KNF];
#pragma unroll
        for (int m = 0; m < KMF; ++m)
#pragma unroll
            for (int n = 0; n < KNF; ++n) acc[m][n] = f32x4{0.f, 0.f, 0.f, 0.f};

        // staging streams: j 0..3 -> idx = wave*4+j: bb = idx>>4, cp = idx&15
        const bool kval = lane < KHW;
        int sbb[4], scq[4];
#pragma unroll
        for (int j = 0; j < 4; ++j) {
            int idx = wave * 4 + j;
            sbb[j] = idx >> 4; scq[j] = (idx & 15) * 2;
        }
        const float* kbase = kin + (size_t)b0 * C * KHW + lane;

        float k0s[4], k1s[4];
#define KA_LOAD(c0_)                                                           \
        _Pragma("unroll")                                                      \
        for (int j = 0; j < 4; ++j) {                                          \
            if (kval) {                                                        \
                const float* p_ = kbase + ((size_t)sbb[j] * C + (c0_) + scq[j]) * KHW; \
                k0s[j] = p_[0]; k1s[j] = p_[KHW];                              \
            }                                                                  \
        }
#define KA_WRITE()                                                             \
        _Pragma("unroll")                                                      \
        for (int j = 0; j < 4; ++j) {                                          \
            if (kval)                                                          \
                *(unsigned int*)&ka[(sbb[j] * KHW + lane) * LDK + scq[j]] =    \
                    pack_bf2(k0s[j], k1s[j]);                                  \
        }

        const unsigned short* wb = wkt + (size_t)(n0 + wn * 32 + lc) * C + lr * 8;

        KA_LOAD(0)
        KA_WRITE()

#pragma unroll 1
        for (int ch = 0; ch < 8; ++ch) {
            const int c0 = ch * 32;
            __syncthreads();

            if (ch < 7) { KA_LOAD(c0 + 32) }

            bf16x8 bcur[KNF], bnxt[KNF];
#pragma unroll
            for (int n = 0; n < KNF; ++n)
                bnxt[n] = *(const bf16x8*)&wb[(size_t)0 + n * (16 * C) + c0];

#pragma unroll
            for (int tap = 0; tap < 9; ++tap) {
                const int dy = tap / 3, dx = tap % 3;
#pragma unroll
                for (int n = 0; n < KNF; ++n) bcur[n] = bnxt[n];
                if (tap < 8) {
#pragma unroll
                    for (int n = 0; n < KNF; ++n)
                        bnxt[n] = *(const bf16x8*)&wb[(size_t)(tap + 1) * (C * C) + n * (16 * C) + c0];
                }
                bf16x8 af[KMF];
#pragma unroll
                for (int m = 0; m < KMF; ++m)
                    af[m] = *(const bf16x8*)&ka[arow[m] + (dy * KW + dx) * LDK];
#pragma unroll
                for (int m = 0; m < KMF; ++m)
#pragma unroll
                    for (int n = 0; n < KNF; ++n)
                        acc[m][n] = __builtin_amdgcn_mfma_f32_16x16x32_bf16(
                            af[m], bcur[n], acc[m][n], 0, 0, 0);
            }

            __syncthreads();
            if (ch < 7) { KA_WRITE() }
        }
#undef KA_LOAD
#undef KA_WRITE

#pragma unroll
        for (int n = 0; n < KNF; ++n) {
            const int co = n0 + wn * 32 + n * 16 + lc;
            const float sc = bkg[co] * rsqrtf(bkv[co] + BN_EPS);
            const float bias = bkb[co] - bkm[co] * sc;
#pragma unroll
            for (int m = 0; m < KMF; ++m) {
                int p = m * 16 + lr * 4;
                int b = b0 + wm;
                f32x4 v = acc[m][n];
                float rr[4] = {fmaxf(v.x + bias, 0.f), fmaxf(v.y + bias, 0.f),
                               fmaxf(v.z + bias, 0.f), fmaxf(v.w + bias, 0.f)};
                float* op = kbuf + ((size_t)b * C + co) * 28 + p;
#pragma unroll
                for (int i = 0; i < 4; ++i)
                    if (p + i < KNPOS) op[i] = rr[i];
            }
        }
        return;
    }

    // ================= SEARCH CONV role =================
    const int wm = wave >> 2, wn = wave & 3;
    const int p0 = (bid & 3) * BM;
    const int b  = bid >> 2;
    const int y0 = p0 / WOUT;
    const int R  = min(ROWS, 31 - y0);
    const int npix = R * 31;

    int arow[MF];
#pragma unroll
    for (int m = 0; m < MF; ++m) {
        int pm = wm * 112 + m * 16 + lc;
        int p = p0 + pm; p = p < NPOS ? p : NPOS - 1;
        int y = p / WOUT, x = p - y * WOUT;
        arow[m] = ((y - y0) * 31 + x) * LDK + lr * 8;
    }

    // A staging: fp32 NCHW direct. Per wave: 2 channel-pairs, 6 px-segments.
    const float* abase = sin_ + (size_t)b * C * 961 + y0 * 31 + lane;
    bool segv[6];
    int dstq[2];
#pragma unroll
    for (int seg = 0; seg < 6; ++seg) segv[seg] = (seg * 64 + lane) < npix;
#pragma unroll
    for (int q = 0; q < 2; ++q) dstq[q] = 2 * (wave + q * 8);

    float a0s[12], a1s[12];
#define SA_LOAD(c0_)                                                           \
    _Pragma("unroll")                                                          \
    for (int q = 0; q < 2; ++q) {                                              \
        const size_t cq_ = (size_t)((c0_) + dstq[q]) * 961;                    \
        _Pragma("unroll")                                                      \
        for (int seg = 0; seg < 6; ++seg) {                                    \
            if (segv[seg]) {                                                   \
                a0s[q * 6 + seg] = abase[cq_ + seg * 64];                      \
                a1s[q * 6 + seg] = abase[cq_ + 961 + seg * 64];                \
            }                                                                  \
        }                                                                      \
    }
#define SA_WRITE(dst_)                                                         \
    _Pragma("unroll")                                                          \
    for (int q = 0; q < 2; ++q) {                                              \
        _Pragma("unroll")                                                      \
        for (int seg = 0; seg < 6; ++seg) {                                    \
            if (segv[seg])                                                     \
                *(unsigned int*)&s_a[(dst_) + (seg * 64 + lane) * LDK + dstq[q]] = \
                    pack_bf2(a0s[q * 6 + seg], a1s[q * 6 + seg]);              \
        }                                                                      \
    }

    // B staging decomposition
    const unsigned short* bptr[BIT]; int boff[BIT];
#pragma unroll
    for (int it = 0; it < BIT; ++it) {
        int i = t + it * 512;
        int n = i >> 2, sl = i & 3;
        bptr[it] = wst + (size_t)n * 256 + sl * 8;
        boff[it] = n * LDK + sl * 8;
    }

    f32x4 acc[MF][NF];
#pragma unroll
    for (int m = 0; m < MF; ++m)
#pragma unroll
        for (int n = 0; n < NF; ++n) acc[m][n] = f32x4{0.f, 0.f, 0.f, 0.f};

    bf16x8 bstg0[BIT], bstg1[BIT];

    // prologue: A chunk 0; B steps 0,1
    SA_LOAD(0)
#pragma unroll
    for (int it = 0; it < BIT; ++it) bstg0[it] = *(const bf16x8*)(bptr[it]);
#pragma unroll
    for (int it = 0; it < BIT; ++it) bstg1[it] = *(const bf16x8*)(bptr[it] + 65536);
    SA_WRITE(0)
#pragma unroll
    for (int it = 0; it < BIT; ++it) *(bf16x8*)&s_b[boff[it]] = bstg0[it];
#pragma unroll
    for (int it = 0; it < BIT; ++it) *(bf16x8*)&s_b[BBUF + boff[it]] = bstg1[it];
    __syncthreads();

#define READ_FRAGS(S, AF, BF)                                                  \
    {                                                                          \
        const int tap_ = (S) % 9;                                              \
        const int dt_ = (tap_ / 3) * 31 + (tap_ % 3);                          \
        const int ab_ = (((S) / 9) & 1) * ABUF;                                \
        const int bb_ = ((S) & 3) * BBUF;                                      \
        _Pragma("unroll")                                                      \
        for (int n = 0; n < NF; ++n)                                           \
            BF[n] = *(const bf16x8*)&s_b[bb_ + (wn * 64 + n * 16 + lc) * LDK + lr * 8]; \
        _Pragma("unroll")                                                      \
        for (int m = 0; m < MF; ++m)                                           \
            AF[m] = *(const bf16x8*)&s_a[ab_ + arow[m] + dt_ * LDK];           \
    }

#define MFMA_STEP(AF, BF)                                                      \
    _Pragma("unroll")                                                          \
    for (int m = 0; m < MF; ++m)                                               \
        _Pragma("unroll")                                                      \
        for (int n = 0; n < NF; ++n)                                           \
            acc[m][n] = __builtin_amdgcn_mfma_f32_16x16x32_bf16(               \
                AF[m], BF[n], acc[m][n], 0, 0, 0);

#pragma unroll 1
    for (int pr = 0; pr < 35; ++pr) {
        const int s0 = 2 * pr, s1 = s0 + 1;

        // A issue at chunk-start pair
        {
            const int cb = (s0 % 9 == 0) ? s0 / 9 : ((s1 % 9 == 0) ? s1 / 9 : -1);
            if (cb >= 0 && cb < 7) {
                const int cn = (cb + 1) * 32;
                SA_LOAD(cn)
            }
        }

        bf16x8 af0[MF], bf0[NF], af1[MF], bf1[NF];
        READ_FRAGS(s0, af0, bf0)
        READ_FRAGS(s1, af1, bf1)

        MFMA_STEP(af0, bf0)

        // mid-pair B global issues for steps s0+2, s1+2
        {
            const int u0 = s0 + 2, u1 = s1 + 2;
            const int t0 = u0 % 9, c0_ = (u0 / 9) * 32;
            const int t1 = u1 % 9, c1_ = (u1 / 9) * 32;
#pragma unroll
            for (int it = 0; it < BIT; ++it)
                bstg0[it] = *(const bf16x8*)(bptr[it] + (size_t)t0 * 65536 + c0_);
#pragma unroll
            for (int it = 0; it < BIT; ++it)
                bstg1[it] = *(const bf16x8*)(bptr[it] + (size_t)t1 * 65536 + c1_);
        }

        MFMA_STEP(af1, bf1)

        // B pair-end writes
        {
            const int w0 = ((s0 + 2) & 3) * BBUF, w1 = ((s1 + 2) & 3) * BBUF;
#pragma unroll
            for (int it = 0; it < BIT; ++it)
                *(bf16x8*)&s_b[w0 + boff[it]] = bstg0[it];
#pragma unroll
            for (int it = 0; it < BIT; ++it)
                *(bf16x8*)&s_b[w1 + boff[it]] = bstg1[it];
        }

        // A write at chunk-end pair
        {
            const int cw = (s0 % 9 == 7) ? s0 / 9 : ((s1 % 9 == 7) ? s1 / 9 : -1);
            if (cw >= 0 && cw < 7) {
                const int dst = ((cw & 1) ^ 1) * ABUF;
                SA_WRITE(dst)
            }
        }
        __syncthreads();
    }

    // final pair: s = 70, 71
    {
        bf16x8 af0[MF], bf0[NF], af1[MF], bf1[NF];
        READ_FRAGS(70, af0, bf0)
        READ_FRAGS(71, af1, bf1)
        MFMA_STEP(af0, bf0)
        MFMA_STEP(af1, bf1)
    }
#undef READ_FRAGS
#undef MFMA_STEP
#undef SA_LOAD
#undef SA_WRITE

    // epilogue: bias + relu -> bf16 planes (padded stride 844)
#pragma unroll
    for (int n = 0; n < NF; ++n) {
        const int co = wn * 64 + n * 16 + lc;
        const float sc = bsg[co] * rsqrtf(bsv[co] + BN_EPS);
        const float bias = bsb[co] - bsm[co] * sc;
#pragma unroll
        for (int m = 0; m < MF; ++m) {
            int pm = wm * 112 + m * 16 + lr * 4;
            int p = p0 + pm;
            f32x4 v = acc[m][n];
            float r0 = fmaxf(v.x + bias, 0.f);
            float r1 = fmaxf(v.y + bias, 0.f);
            float r2 = fmaxf(v.z + bias, 0.f);
            float r3 = fmaxf(v.w + bias, 0.f);
            unsigned short* op = sbuf + ((size_t)b * C + co) * 844 + p;
            if (p + 4 <= NPOS) {
                ushort4 pk;
                pk.x = f2bf(r0); pk.y = f2bf(r1); pk.z = f2bf(r2); pk.w = f2bf(r3);
                *(ushort4*)op = pk;
            } else {
                float rr[4] = {r0, r1, r2, r3};
#pragma unroll
                for (int i = 0; i < 4; ++i)
                    if (p + i < NPOS) op[i] = f2bf(rr[i]);
            }
        }
    }
}

// ---------------------------------------------------------------------------
// Depthwise 5x5 valid xcorr: 2 channels/block, 5 outputs/thread (5x9 window).
// ---------------------------------------------------------------------------
__global__ __launch_bounds__(256) void xcorr_dw(
    const unsigned short* __restrict__ s, const float* __restrict__ k,
    float* __restrict__ out)
{
    const int bc0 = blockIdx.x * 2;
    const int t = threadIdx.x;

    __shared__ float s_s[2][844];
    __shared__ float s_k[2][25];

#pragma unroll
    for (int it = 0; it < 2; ++it) {
        int i = t + it * 256;
        if (i < 422) {
            int pl = i < 211 ? 0 : 1;
            int q = i - pl * 211;
            ushort4 v = *(const ushort4*)(s + (size_t)(bc0 + pl) * 844 + 4 * q);
            s_s[pl][4 * q + 0] = bf2f(v.x);
            s_s[pl][4 * q + 1] = bf2f(v.y);
            s_s[pl][4 * q + 2] = bf2f(v.z);
            s_s[pl][4 * q + 3] = bf2f(v.w);
        }
    }
    if (t < 50) s_k[t / 25][t % 25] = k[(size_t)(bc0 + t / 25) * 28 + t % 25];
    __syncthreads();

    if (t >= 250) return;
    const int ch = t / 125;
    const int r = t - ch * 125;
    const int y = r / 5;
    const int xb = (r - y * 5) * 5;

    float kk[25];
#pragma unroll
    for (int i = 0; i < 25; ++i) kk[i] = s_k[ch][i];

    float w[5][9];
#pragma unroll
    for (int dy = 0; dy < 5; ++dy)
#pragma unroll
        for (int dx = 0; dx < 9; ++dx)
            w[dy][dx] = s_s[ch][(y + dy) * 29 + xb + dx];

    float o[5] = {0.f, 0.f, 0.f, 0.f, 0.f};
#pragma unroll
    for (int dy = 0; dy < 5; ++dy)
#pragma unroll
        for (int dx = 0; dx < 5; ++dx) {
            const float kv = kk[dy * 5 + dx];
#pragma unroll
            for (int oo = 0; oo < 5; ++oo)
                o[oo] += w[dy][oo + dx] * kv;
        }

    float* op = out + (size_t)(bc0 + ch) * 625 + y * 25 + xb;
#pragma unroll
    for (int oo = 0; oo < 5; ++oo) op[oo] = o[oo];
}

extern "C" void kernel_launch(void* const* d_in, const int* in_sizes, int n_in,
                              void* d_out, int out_size, void* d_ws, size_t ws_size,
                              hipStream_t stream) {
    const float* kin = (const float*)d_in[0];   // [128,256,7,7]
    const float* sin_ = (const float*)d_in[1];  // [128,256,31,31]
    const float* wk = (const float*)d_in[2];
    const float* bkg = (const float*)d_in[3];
    const float* bkb = (const float*)d_in[4];
    const float* bkm = (const float*)d_in[5];
    const float* bkv = (const float*)d_in[6];
    const float* ws_ = (const float*)d_in[7];
    const float* bsg = (const float*)d_in[8];
    const float* bsb = (const float*)d_in[9];
    const float* bsm = (const float*)d_in[10];
    const float* bsv = (const float*)d_in[11];
    float* out = (float*)d_out;

    // workspace: wkt | wst | sbuf bf16 [128][256][844] | kbuf f32 [128][256][28]
    char* base = (char*)d_ws;
    unsigned short* wkt = (unsigned short*)base;               // 1,179,648 B
    unsigned short* wst = wkt + (size_t)9 * C * C;             // 1,179,648 B
    unsigned short* sbuf = (unsigned short*)(base + 2359296);  // 55,312,384 B
    float* kbuf = (float*)(base + 2359296 + 55312384);         //  3,670,016 B

    // L1: weight prep (both convs)
    wprep_both<<<512, 256, 0, stream>>>(wk, bkg, bkv, wkt, ws_, bsg, bsv, wst);

    // L2: search conv (512 blocks) + kernel conv (128 blocks), transpose-free
    mega_conv<<<640, 512, 0, stream>>>(
        sin_, kin, wst, wkt,
        bsg, bsb, bsm, bsv, bkg, bkb, bkm, bkv,
        sbuf, kbuf);

    // L3: depthwise xcorr
    xcorr_dw<<<128 * (C / 2), 256, 0, stream>>>(sbuf, kbuf, out);
}